// Round 1
// baseline (5011.379 us; speedup 1.0000x reference)
//
#include <hip/hip_runtime.h>
#include <math.h>

// Problem constants
constexpr int T_SEQ = 2049;
constexpr int D_MODEL = 1024;
constexpr int N_HEAD = 16;
constexpr int HEAD_DIM = 64;

// ---------------------------------------------------------------------------
// GEMM: C = A(M x 1024) @ W(1024 x 1024)^T + bias
// MODE 0: write head-major  C[h][m][hd]  (h = n>>6, hd = n&63), no bias-skip
// MODE 1: write row-major   C[m][n]
// Block: 256 threads, 64x64 tile, BK=16, each thread 4x4 microtile.
// ---------------------------------------------------------------------------
template <int MODE>
__global__ __launch_bounds__(256) void gemm_bt(const float* __restrict__ A,
                                               const float* __restrict__ W,
                                               const float* __restrict__ bias,
                                               float* __restrict__ C, int M) {
  constexpr int K = 1024;
  constexpr int LDP = 68;  // padded LDS row stride (16B-aligned, conflict-safe)
  __shared__ float As[16][LDP];
  __shared__ float Ws[16][LDP];

  const int tid = threadIdx.x;
  const int m0 = blockIdx.y * 64;
  const int n0 = blockIdx.x * 64;
  const int tx = tid & 15;   // 0..15 -> col group
  const int ty = tid >> 4;   // 0..15 -> row group

  const int lrow = tid >> 2;        // 0..63 tile row loaded by this thread
  const int lc4 = (tid & 3) * 4;    // 0,4,8,12 k-col (float4)
  const bool aValid = (m0 + lrow) < M;
  const float* Arow = A + (size_t)(m0 + lrow) * K + lc4;
  const float* Wrow = W + (size_t)(n0 + lrow) * K + lc4;

  float acc[4][4] = {};

  for (int k0 = 0; k0 < K; k0 += 16) {
    float4 av = aValid ? *(const float4*)(Arow + k0) : make_float4(0.f, 0.f, 0.f, 0.f);
    float4 wv = *(const float4*)(Wrow + k0);
    As[lc4 + 0][lrow] = av.x;
    As[lc4 + 1][lrow] = av.y;
    As[lc4 + 2][lrow] = av.z;
    As[lc4 + 3][lrow] = av.w;
    Ws[lc4 + 0][lrow] = wv.x;
    Ws[lc4 + 1][lrow] = wv.y;
    Ws[lc4 + 2][lrow] = wv.z;
    Ws[lc4 + 3][lrow] = wv.w;
    __syncthreads();
#pragma unroll
    for (int kk = 0; kk < 16; kk++) {
      float4 a4 = *(const float4*)&As[kk][ty * 4];
      float4 b4 = *(const float4*)&Ws[kk][tx * 4];
      float ar[4] = {a4.x, a4.y, a4.z, a4.w};
      float br[4] = {b4.x, b4.y, b4.z, b4.w};
#pragma unroll
      for (int i = 0; i < 4; i++)
#pragma unroll
        for (int j = 0; j < 4; j++) acc[i][j] += ar[i] * br[j];
    }
    __syncthreads();
  }

#pragma unroll
  for (int i = 0; i < 4; i++) {
    const int m = m0 + ty * 4 + i;
    if (m >= M) continue;
#pragma unroll
    for (int j = 0; j < 4; j++) {
      const int n = n0 + tx * 4 + j;
      const float val = acc[i][j] + bias[n];
      if (MODE == 0) {
        const int h = n >> 6;
        const int hd = n & 63;
        C[((size_t)h * T_SEQ + m) * HEAD_DIM + hd] = val;
      } else {
        C[(size_t)m * D_MODEL + n] = val;
      }
    }
  }
}

// ---------------------------------------------------------------------------
// Attention: one block (256 threads) per (query row t, head h).
// scores[s] = (q[t]·k[s] + q[t+1]·Er[s]) / 8  for s<=t  (q[T] treated as 0)
// softmax over s, then ctx[t][h*64+hd] = sum_s p[s] * v[s][hd]
// ---------------------------------------------------------------------------
__global__ __launch_bounds__(256) void attn_kernel(const float* __restrict__ qh,
                                                   const float* __restrict__ kh,
                                                   const float* __restrict__ vh,
                                                   const float* __restrict__ Er,
                                                   float* __restrict__ ctx) {
  const int t = blockIdx.x;
  const int h = blockIdx.y;
  const int tid = threadIdx.x;

  __shared__ float sc[T_SEQ];
  __shared__ float qab[128];  // [0..63]=q[t], [64..127]=q[t+1] (or 0)
  __shared__ float red[256];
  __shared__ float vpart[4][64];

  const float* qbase = qh + ((size_t)h * T_SEQ + t) * HEAD_DIM;
  if (tid < 64) {
    qab[tid] = qbase[tid];
  } else if (tid < 128) {
    // qbase[tid] == qh[h][t+1][tid-64] because the row stride is 64
    qab[tid] = (t + 1 < T_SEQ) ? qbase[tid] : 0.f;
  }
  __syncthreads();

  const float4* qa4 = (const float4*)qab;
  const float4* qb4 = (const float4*)(qab + 64);

  float lmax = -INFINITY;
  for (int s = tid; s <= t; s += 256) {
    const float4* kr = (const float4*)(kh + ((size_t)h * T_SEQ + s) * HEAD_DIM);
    const float4* er = (const float4*)(Er + (size_t)s * HEAD_DIM);
    float acc = 0.f;
#pragma unroll
    for (int j = 0; j < 16; j++) {
      float4 a = qa4[j];
      float4 kv = kr[j];
      float4 b = qb4[j];
      float4 ev = er[j];
      acc += a.x * kv.x + a.y * kv.y + a.z * kv.z + a.w * kv.w;
      acc += b.x * ev.x + b.y * ev.y + b.z * ev.z + b.w * ev.w;
    }
    const float val = acc * 0.125f;  // 1/sqrt(64)
    sc[s] = val;
    lmax = fmaxf(lmax, val);
  }

  // block-reduce max
  red[tid] = lmax;
  __syncthreads();
  for (int off = 128; off > 0; off >>= 1) {
    if (tid < off) red[tid] = fmaxf(red[tid], red[tid + off]);
    __syncthreads();
  }
  const float mval = red[0];
  __syncthreads();

  // exp + local sum
  float lsum = 0.f;
  for (int s = tid; s <= t; s += 256) {
    const float e = __expf(sc[s] - mval);
    sc[s] = e;
    lsum += e;
  }
  red[tid] = lsum;
  __syncthreads();
  for (int off = 128; off > 0; off >>= 1) {
    if (tid < off) red[tid] += red[tid + off];
    __syncthreads();
  }
  const float inv = 1.0f / red[0];

  // weighted V accumulation: 4 s-partitions x 64 head-dims
  const int hd = tid & 63;
  const int part = tid >> 6;
  float acc = 0.f;
  for (int s = part; s <= t; s += 4) {
    acc += sc[s] * vh[((size_t)h * T_SEQ + s) * HEAD_DIM + hd];
  }
  vpart[part][hd] = acc;
  __syncthreads();
  if (tid < 64) {
    const float r =
        (vpart[0][tid] + vpart[1][tid] + vpart[2][tid] + vpart[3][tid]) * inv;
    ctx[(size_t)t * D_MODEL + h * HEAD_DIM + tid] = r;
  }
}

// ---------------------------------------------------------------------------
extern "C" void kernel_launch(void* const* d_in, const int* in_sizes, int n_in,
                              void* d_out, int out_size, void* d_ws, size_t ws_size,
                              hipStream_t stream) {
  const float* q = (const float*)d_in[0];
  const float* k = (const float*)d_in[1];
  const float* v = (const float*)d_in[2];
  // d_in[3] = mask (tril, causal) -- handled implicitly
  const float* Wq_w = (const float*)d_in[4];
  const float* Wq_b = (const float*)d_in[5];
  const float* Wk_w = (const float*)d_in[6];
  const float* Wk_b = (const float*)d_in[7];
  const float* Wv_w = (const float*)d_in[8];
  const float* Wv_b = (const float*)d_in[9];
  const float* Er = (const float*)d_in[10];
  const float* Wo_w = (const float*)d_in[11];
  const float* Wo_b = (const float*)d_in[12];
  float* out = (float*)d_out;

  float* ws = (float*)d_ws;
  const size_t plane = (size_t)T_SEQ * D_MODEL;  // 2,098,176 floats
  float* qh = ws;
  float* kh = ws + plane;
  float* vh = ws + 2 * plane;
  float* ctx = ws + 3 * plane;

  const dim3 gblk(256);
  const dim3 ggrid(D_MODEL / 64, (T_SEQ + 63) / 64);  // (16, 33)

  gemm_bt<0><<<ggrid, gblk, 0, stream>>>(q, Wq_w, Wq_b, qh, T_SEQ);
  gemm_bt<0><<<ggrid, gblk, 0, stream>>>(k, Wk_w, Wk_b, kh, T_SEQ);
  gemm_bt<0><<<ggrid, gblk, 0, stream>>>(v, Wv_w, Wv_b, vh, T_SEQ);

  attn_kernel<<<dim3(T_SEQ, N_HEAD), gblk, 0, stream>>>(qh, kh, vh, Er, ctx);

  gemm_bt<1><<<ggrid, gblk, 0, stream>>>(ctx, Wo_w, Wo_b, out, T_SEQ);
}

// Round 2
// 594.014 us; speedup vs baseline: 8.4365x; 8.4365x over previous
//
#include <hip/hip_runtime.h>
#include <hip/hip_bf16.h>
#include <math.h>

constexpr int T_SEQ = 2049;
constexpr int D_MODEL = 1024;
constexpr int N_HEAD = 16;
constexpr int HEAD_DIM = 64;
constexpr int VT_STRIDE = 2056;  // padded s-stride for transposed V (16B-aligned rows)

typedef __attribute__((ext_vector_type(8))) short short8;
typedef __attribute__((ext_vector_type(4))) float floatx4;

// ---------------------------------------------------------------------------
// GEMM: C = A(M x 1024) @ W(1024 x 1024)^T + bias
// MODE 0: write bf16 head-major  C[h][m][hd]  (h = n>>6, hd = n&63)
// MODE 1: write fp32 row-major   C[m][n]
// ---------------------------------------------------------------------------
template <int MODE>
__global__ __launch_bounds__(256) void gemm_bt(const float* __restrict__ A,
                                               const float* __restrict__ W,
                                               const float* __restrict__ bias,
                                               void* __restrict__ Cout, int M) {
  constexpr int K = 1024;
  constexpr int LDP = 68;
  __shared__ float As[16][LDP];
  __shared__ float Ws[16][LDP];

  const int tid = threadIdx.x;
  const int m0 = blockIdx.y * 64;
  const int n0 = blockIdx.x * 64;
  const int tx = tid & 15;
  const int ty = tid >> 4;

  const int lrow = tid >> 2;
  const int lc4 = (tid & 3) * 4;
  const bool aValid = (m0 + lrow) < M;
  const float* Arow = A + (size_t)(m0 + lrow) * K + lc4;
  const float* Wrow = W + (size_t)(n0 + lrow) * K + lc4;

  float acc[4][4] = {};

  for (int k0 = 0; k0 < K; k0 += 16) {
    float4 av = aValid ? *(const float4*)(Arow + k0) : make_float4(0.f, 0.f, 0.f, 0.f);
    float4 wv = *(const float4*)(Wrow + k0);
    As[lc4 + 0][lrow] = av.x;
    As[lc4 + 1][lrow] = av.y;
    As[lc4 + 2][lrow] = av.z;
    As[lc4 + 3][lrow] = av.w;
    Ws[lc4 + 0][lrow] = wv.x;
    Ws[lc4 + 1][lrow] = wv.y;
    Ws[lc4 + 2][lrow] = wv.z;
    Ws[lc4 + 3][lrow] = wv.w;
    __syncthreads();
#pragma unroll
    for (int kk = 0; kk < 16; kk++) {
      float4 a4 = *(const float4*)&As[kk][ty * 4];
      float4 b4 = *(const float4*)&Ws[kk][tx * 4];
      float ar[4] = {a4.x, a4.y, a4.z, a4.w};
      float br[4] = {b4.x, b4.y, b4.z, b4.w};
#pragma unroll
      for (int i = 0; i < 4; i++)
#pragma unroll
        for (int j = 0; j < 4; j++) acc[i][j] += ar[i] * br[j];
    }
    __syncthreads();
  }

#pragma unroll
  for (int i = 0; i < 4; i++) {
    const int m = m0 + ty * 4 + i;
    if (m >= M) continue;
#pragma unroll
    for (int j = 0; j < 4; j++) {
      const int n = n0 + tx * 4 + j;
      const float val = acc[i][j] + bias[n];
      if (MODE == 0) {
        const int h = n >> 6;
        const int hd = n & 63;
        ((__hip_bfloat16*)Cout)[((size_t)h * T_SEQ + m) * HEAD_DIM + hd] =
            __float2bfloat16(val);
      } else {
        ((float*)Cout)[(size_t)m * D_MODEL + n] = val;
      }
    }
  }
}

// ---------------------------------------------------------------------------
// fp32 -> bf16 elementwise (for Er)
// ---------------------------------------------------------------------------
__global__ void cvt_bf16(const float* __restrict__ in, __hip_bfloat16* __restrict__ out,
                         int n) {
  int i = blockIdx.x * 256 + threadIdx.x;
  if (i < n) out[i] = __float2bfloat16(in[i]);
}

// ---------------------------------------------------------------------------
// Transpose V per head: vh[h][t][d] -> vt[h][d][t] (t padded to VT_STRIDE, pad=0)
// ---------------------------------------------------------------------------
__global__ __launch_bounds__(256) void transpose_v(const __hip_bfloat16* __restrict__ vh,
                                                   __hip_bfloat16* __restrict__ vt) {
  __shared__ __align__(16) __hip_bfloat16 tile[64][72];
  const int t0 = blockIdx.x * 64;
  const int h = blockIdx.y;
  const int tid = threadIdx.x;
  const short* plane = (const short*)(vh + (size_t)h * T_SEQ * HEAD_DIM);
  short* oplane = (short*)(vt + (size_t)h * HEAD_DIM * VT_STRIDE);

  for (int idx = tid; idx < 64 * 8; idx += 256) {
    const int row = idx >> 3, ch = idx & 7;
    const int t = t0 + row;
    short8 v = {0, 0, 0, 0, 0, 0, 0, 0};
    if (t < T_SEQ) v = *(const short8*)(plane + (size_t)t * HEAD_DIM + ch * 8);
    *(short8*)&tile[row][ch * 8] = v;
  }
  __syncthreads();
  for (int idx = tid; idx < 64 * 8; idx += 256) {
    const int d = idx >> 3, ch = idx & 7;
    if (t0 + ch * 8 < VT_STRIDE) {
      short8 v;
#pragma unroll
      for (int i = 0; i < 8; i++) v[i] = *(const short*)&tile[ch * 8 + i][d];
      *(short8*)(oplane + (size_t)d * VT_STRIDE + t0 + ch * 8) = v;
    }
  }
}

// ---------------------------------------------------------------------------
// Flash attention with relative position, bf16 MFMA 16x16x32.
// S[t][s] = q[t].k[s] + q[t+1].Er[s]  ==  [Q|Q+1](64x128) @ [K|Er](64x128)^T
// Block = 256 threads (4 waves), BM=64 q-rows, BN=64 k-cols per iter.
// Wave w owns q-row strip [w*16, w*16+16); softmax state in registers.
// ---------------------------------------------------------------------------
__global__ __launch_bounds__(256) void flash_attn(
    const __hip_bfloat16* __restrict__ qh, const __hip_bfloat16* __restrict__ kh,
    const __hip_bfloat16* __restrict__ er, const __hip_bfloat16* __restrict__ vt,
    float* __restrict__ ctx) {
  constexpr int LKQ = 136;  // 128 + 8 pad (16B-aligned rows)
  constexpr int LVP = 72;   // 64 + 8 pad
  __shared__ __align__(16) __hip_bfloat16 Qs[64][LKQ];
  __shared__ __align__(16) __hip_bfloat16 Ks[64][LKQ];
  __shared__ __align__(16) __hip_bfloat16 Vt[64][LVP];
  __shared__ __align__(16) __hip_bfloat16 Ps[64][LVP];

  const int tid = threadIdx.x;
  const int h = blockIdx.y;
  // work-balance swizzle: alternate heavy/light q-tiles across heads
  const int qt = (h & 1) ? (32 - blockIdx.x) : blockIdx.x;

  const int wave = tid >> 6;
  const int lane = tid & 63;
  const int col = lane & 15;
  const int quad = lane >> 4;

  const short* qplane = (const short*)(qh + (size_t)h * T_SEQ * HEAD_DIM);
  const short* kplane = (const short*)(kh + (size_t)h * T_SEQ * HEAD_DIM);
  const short* eplane = (const short*)er;
  const short* vplane = (const short*)(vt + (size_t)h * HEAD_DIM * VT_STRIDE);

  // ---- load Q tile: cols 0..63 = q[t], 64..127 = q[t+1] (row stride 64 makes
  // q[t] col 64+x == plane[t*64 + 64 + x], so one contiguous read per chunk)
  for (int idx = tid; idx < 64 * 16; idx += 256) {
    const int row = idx >> 4, ch = idx & 15;
    const int off = (qt * 64 + row) * HEAD_DIM + ch * 8;
    short8 v = {0, 0, 0, 0, 0, 0, 0, 0};
    if (off + 8 <= T_SEQ * HEAD_DIM) v = *(const short8*)(qplane + off);
    *(short8*)&Qs[row][ch * 8] = v;
  }

  floatx4 o[4];
  float m_i[4], l_i[4];
#pragma unroll
  for (int i = 0; i < 4; i++) {
    o[i] = (floatx4){0.f, 0.f, 0.f, 0.f};
    m_i[i] = -INFINITY;
    l_i[i] = 0.f;
  }

  for (int j = 0; j <= qt; ++j) {
    if (j) __syncthreads();  // previous iter's LDS reads complete
    const int s0 = j * 64;
    // ---- stage K|Er tile (64 x 128) and V^T tile (64 x 64)
    for (int idx = tid; idx < 64 * 16; idx += 256) {
      const int row = idx >> 4, ch = idx & 15;
      const int s = s0 + row;
      short8 v = {0, 0, 0, 0, 0, 0, 0, 0};
      if (s < T_SEQ) {
        v = (ch < 8) ? *(const short8*)(kplane + (size_t)s * HEAD_DIM + ch * 8)
                     : *(const short8*)(eplane + (size_t)s * HEAD_DIM + (ch - 8) * 8);
      }
      *(short8*)&Ks[row][ch * 8] = v;
    }
    for (int idx = tid; idx < 64 * 8; idx += 256) {
      const int d = idx >> 3, ch = idx & 7;
      short8 v = {0, 0, 0, 0, 0, 0, 0, 0};
      if (s0 + ch * 8 + 8 <= VT_STRIDE)
        v = *(const short8*)(vplane + (size_t)d * VT_STRIDE + s0 + ch * 8);
      *(short8*)&Vt[d][ch * 8] = v;
    }
    __syncthreads();

    // ---- S = Qaug @ Kaug^T  (wave strip 16 x 64, K=128)
    short8 aq[4];
#pragma unroll
    for (int kc = 0; kc < 4; kc++)
      aq[kc] = *(const short8*)&Qs[wave * 16 + col][kc * 32 + quad * 8];

    floatx4 s[4];
#pragma unroll
    for (int ct = 0; ct < 4; ct++) {
      floatx4 c = {0.f, 0.f, 0.f, 0.f};
#pragma unroll
      for (int kc = 0; kc < 4; kc++) {
        short8 b = *(const short8*)&Ks[ct * 16 + col][kc * 32 + quad * 8];
        c = __builtin_amdgcn_mfma_f32_16x16x32_bf16(aq[kc], b, c, 0, 0, 0);
      }
      s[ct] = c;
    }

    // ---- causal mask (diagonal tile only; j<qt tiles are fully visible)
    if (j == qt) {
      const int trow = qt * 64 + wave * 16 + quad * 4;
#pragma unroll
      for (int ct = 0; ct < 4; ct++) {
        const int scol = s0 + ct * 16 + col;
#pragma unroll
        for (int r = 0; r < 4; r++)
          if (scol > trow + r) s[ct][r] = -INFINITY;
      }
    }

    // ---- online softmax (row r lives in 16 lanes of this quad-group)
#pragma unroll
    for (int r = 0; r < 4; r++) {
      float mx = fmaxf(fmaxf(s[0][r], s[1][r]), fmaxf(s[2][r], s[3][r]));
#pragma unroll
      for (int off = 1; off <= 8; off <<= 1) mx = fmaxf(mx, __shfl_xor(mx, off, 64));
      const float mnew = fmaxf(m_i[r], mx);
      const float alpha = __expf((m_i[r] - mnew) * 0.125f);
      m_i[r] = mnew;
      float rs = 0.f;
#pragma unroll
      for (int ct = 0; ct < 4; ct++) {
        const float p = __expf((s[ct][r] - mnew) * 0.125f);
        s[ct][r] = p;
        rs += p;
      }
#pragma unroll
      for (int off = 1; off <= 8; off <<= 1) rs += __shfl_xor(rs, off, 64);
      l_i[r] = l_i[r] * alpha + rs;
#pragma unroll
      for (int nt = 0; nt < 4; nt++) o[nt][r] *= alpha;
    }

    // ---- P (C-layout) -> LDS -> A-layout for PV
#pragma unroll
    for (int ct = 0; ct < 4; ct++)
#pragma unroll
      for (int r = 0; r < 4; r++)
        Ps[wave * 16 + quad * 4 + r][ct * 16 + col] = __float2bfloat16(s[ct][r]);
    __syncthreads();  // also orders Ps write->read against type-punned pointers

    short8 pa[2];
#pragma unroll
    for (int kc = 0; kc < 2; kc++)
      pa[kc] = *(const short8*)&Ps[wave * 16 + col][kc * 32 + quad * 8];
#pragma unroll
    for (int nt = 0; nt < 4; nt++)
#pragma unroll
      for (int kc = 0; kc < 2; kc++) {
        short8 b = *(const short8*)&Vt[nt * 16 + col][kc * 32 + quad * 8];
        o[nt] = __builtin_amdgcn_mfma_f32_16x16x32_bf16(pa[kc], b, o[nt], 0, 0, 0);
      }
  }

  // ---- epilogue: normalize and store ctx[t][h*64 + d] (fp32)
  const int trow = qt * 64 + wave * 16 + quad * 4;
#pragma unroll
  for (int r = 0; r < 4; r++) {
    const int t = trow + r;
    if (t < T_SEQ) {
      const float iv = 1.0f / l_i[r];
#pragma unroll
      for (int nt = 0; nt < 4; nt++)
        ctx[(size_t)t * D_MODEL + h * HEAD_DIM + nt * 16 + col] = o[nt][r] * iv;
    }
  }
}

// ---------------------------------------------------------------------------
extern "C" void kernel_launch(void* const* d_in, const int* in_sizes, int n_in,
                              void* d_out, int out_size, void* d_ws, size_t ws_size,
                              hipStream_t stream) {
  const float* q = (const float*)d_in[0];
  const float* k = (const float*)d_in[1];
  const float* v = (const float*)d_in[2];
  const float* Wq_w = (const float*)d_in[4];
  const float* Wq_b = (const float*)d_in[5];
  const float* Wk_w = (const float*)d_in[6];
  const float* Wk_b = (const float*)d_in[7];
  const float* Wv_w = (const float*)d_in[8];
  const float* Wv_b = (const float*)d_in[9];
  const float* Er = (const float*)d_in[10];
  const float* Wo_w = (const float*)d_in[11];
  const float* Wo_b = (const float*)d_in[12];
  float* out = (float*)d_out;

  // workspace carve-up (byte offsets, all 16B-aligned)
  char* ws = (char*)d_ws;
  const size_t plane_bf = (size_t)N_HEAD * T_SEQ * HEAD_DIM * sizeof(__hip_bfloat16);
  __hip_bfloat16* qh_bf = (__hip_bfloat16*)ws;
  __hip_bfloat16* kh_bf = (__hip_bfloat16*)(ws + plane_bf);
  __hip_bfloat16* vh_bf = (__hip_bfloat16*)(ws + 2 * plane_bf);
  __hip_bfloat16* er_bf = (__hip_bfloat16*)(ws + 3 * plane_bf);
  char* p = ws + 3 * plane_bf + (size_t)T_SEQ * HEAD_DIM * sizeof(__hip_bfloat16);
  __hip_bfloat16* vh_t = (__hip_bfloat16*)p;
  p += (size_t)N_HEAD * HEAD_DIM * VT_STRIDE * sizeof(__hip_bfloat16);
  float* ctx = (float*)p;

  const dim3 gblk(256);
  const dim3 ggrid(D_MODEL / 64, (T_SEQ + 63) / 64);  // (16, 33)

  gemm_bt<0><<<ggrid, gblk, 0, stream>>>(q, Wq_w, Wq_b, qh_bf, T_SEQ);
  gemm_bt<0><<<ggrid, gblk, 0, stream>>>(k, Wk_w, Wk_b, kh_bf, T_SEQ);
  gemm_bt<0><<<ggrid, gblk, 0, stream>>>(v, Wv_w, Wv_b, vh_bf, T_SEQ);

  cvt_bf16<<<dim3((T_SEQ * HEAD_DIM + 255) / 256), gblk, 0, stream>>>(
      Er, er_bf, T_SEQ * HEAD_DIM);
  transpose_v<<<dim3((T_SEQ + 63) / 64, N_HEAD), gblk, 0, stream>>>(vh_bf, vh_t);

  flash_attn<<<dim3((T_SEQ + 63) / 64, N_HEAD), gblk, 0, stream>>>(qh_bf, kh_bf, er_bf,
                                                                   vh_t, ctx);

  gemm_bt<1><<<ggrid, gblk, 0, stream>>>(ctx, Wo_w, Wo_b, out, T_SEQ);
}

// Round 3
// 333.786 us; speedup vs baseline: 15.0138x; 1.7796x over previous
//
#include <hip/hip_runtime.h>
#include <hip/hip_bf16.h>
#include <math.h>

constexpr int T_SEQ = 2049;
constexpr int D_MODEL = 1024;
constexpr int N_HEAD = 16;
constexpr int HEAD_DIM = 64;
constexpr int VT_STRIDE = 2056;  // padded s-stride for transposed V

typedef __attribute__((ext_vector_type(8))) short short8;
typedef __attribute__((ext_vector_type(4))) float floatx4;

// async global->LDS, 16B per lane; LDS dest = base + lane*16
__device__ inline void load_lds16(const void* g, void* l) {
  __builtin_amdgcn_global_load_lds(
      (const __attribute__((address_space(1))) unsigned int*)g,
      (__attribute__((address_space(3))) unsigned int*)l, 16, 0, 0);
}

__device__ inline short8 cvt8_bf16(const float* p) {
  float4 a = *(const float4*)p, b = *(const float4*)(p + 4);
  __hip_bfloat16 t[8] = {__float2bfloat16(a.x), __float2bfloat16(a.y),
                         __float2bfloat16(a.z), __float2bfloat16(a.w),
                         __float2bfloat16(b.x), __float2bfloat16(b.y),
                         __float2bfloat16(b.z), __float2bfloat16(b.w)};
  return *(const short8*)t;
}

// ---------------------------------------------------------------------------
// batched fp32 -> bf16 cast (z selects tensor), 8 elems/thread
// ---------------------------------------------------------------------------
__global__ __launch_bounds__(256) void cast_bf16x(
    const float* __restrict__ i0, const float* __restrict__ i1,
    const float* __restrict__ i2, const float* __restrict__ i3,
    __hip_bfloat16* __restrict__ o0, __hip_bfloat16* __restrict__ o1,
    __hip_bfloat16* __restrict__ o2, __hip_bfloat16* __restrict__ o3, int n) {
  const int z = blockIdx.y;
  const float* in = z == 0 ? i0 : z == 1 ? i1 : z == 2 ? i2 : i3;
  __hip_bfloat16* out = z == 0 ? o0 : z == 1 ? o1 : z == 2 ? o2 : o3;
  const int i = (blockIdx.x * 256 + threadIdx.x) * 8;
  if (i + 8 > n) return;
  *(short8*)(out + i) = cvt8_bf16(in + i);
}

// ---------------------------------------------------------------------------
// bf16 MFMA GEMM: C[M x 1024] = A[M x 1024] @ W[1024 x 1024]^T + bias
// 128x128 tile, BK=32, 256 threads (2x2 waves, 64x64 each).
// global_load_lds staging with XOR chunk swizzle: chunk c of row r lives at
// slot c ^ ((r>>1)&3)  -> fragment ds_read_b128 is 2-way (free).
// OUT_BF16: 1 -> bf16 row-major, 0 -> fp32 row-major.
// grid.z selects (A,W,bias,C) triple for fused QKV.
// ---------------------------------------------------------------------------
template <int OUT_BF16>
__global__ __launch_bounds__(256) void mfma_gemm(
    const __hip_bfloat16* __restrict__ A0, const __hip_bfloat16* __restrict__ A1,
    const __hip_bfloat16* __restrict__ A2, const __hip_bfloat16* __restrict__ W0,
    const __hip_bfloat16* __restrict__ W1, const __hip_bfloat16* __restrict__ W2,
    const float* __restrict__ bias0, const float* __restrict__ bias1,
    const float* __restrict__ bias2, void* C0, void* C1, void* C2, int M) {
  constexpr int K = D_MODEL;
  __shared__ __align__(16) __hip_bfloat16 As[128 * 32];
  __shared__ __align__(16) __hip_bfloat16 Bs[128 * 32];

  const int z = blockIdx.z;
  const short* A = (const short*)(z == 0 ? A0 : z == 1 ? A1 : A2);
  const short* W = (const short*)(z == 0 ? W0 : z == 1 ? W1 : W2);
  const float* bias = z == 0 ? bias0 : z == 1 ? bias1 : bias2;
  void* C = z == 0 ? C0 : z == 1 ? C1 : C2;

  const int tid = threadIdx.x;
  const int wave = tid >> 6, lane = tid & 63;
  const int col = lane & 15, quad = lane >> 4;
  const int wm = wave >> 1, wn = wave & 1;
  const int m0 = blockIdx.y * 128, n0 = blockIdx.x * 128;

  // staging lane geometry: 16 rows x 4 slots per instruction
  const int sr = lane >> 2;
  const int ss = lane & 3;
  const int sch = ss ^ ((sr >> 1) & 3);  // global chunk this lane fetches

  floatx4 acc[4][4];
#pragma unroll
  for (int i = 0; i < 4; i++)
#pragma unroll
    for (int j = 0; j < 4; j++) acc[i][j] = (floatx4){0.f, 0.f, 0.f, 0.f};

  for (int k0 = 0; k0 < K; k0 += 32) {
    if (k0) __syncthreads();
#pragma unroll
    for (int i = 0; i < 2; i++) {
      const int rb = wave * 32 + i * 16;  // tile-row base for this instr
      const int am = min(m0 + rb + sr, M - 1);
      load_lds16(A + (size_t)am * K + k0 + sch * 8, (char*)As + rb * 64);
      const int bn = n0 + rb + sr;  // always < 1024
      load_lds16(W + (size_t)bn * K + k0 + sch * 8, (char*)Bs + rb * 64);
    }
    __syncthreads();

    short8 af[4], bf[4];
#pragma unroll
    for (int t = 0; t < 4; t++) {
      const int ra = wm * 64 + t * 16 + col;
      af[t] = *(const short8*)(As + ra * 32 + (quad ^ ((ra >> 1) & 3)) * 8);
      const int rb = wn * 64 + t * 16 + col;
      bf[t] = *(const short8*)(Bs + rb * 32 + (quad ^ ((rb >> 1) & 3)) * 8);
    }
#pragma unroll
    for (int mt = 0; mt < 4; mt++)
#pragma unroll
      for (int nt = 0; nt < 4; nt++)
        acc[mt][nt] =
            __builtin_amdgcn_mfma_f32_16x16x32_bf16(af[mt], bf[nt], acc[mt][nt], 0, 0, 0);
  }

#pragma unroll
  for (int mt = 0; mt < 4; mt++) {
#pragma unroll
    for (int r = 0; r < 4; r++) {
      const int m = m0 + wm * 64 + mt * 16 + quad * 4 + r;
      if (m >= M) continue;
#pragma unroll
      for (int nt = 0; nt < 4; nt++) {
        const int n = n0 + wn * 64 + nt * 16 + col;
        const float val = acc[mt][nt][r] + bias[n];
        if (OUT_BF16)
          ((__hip_bfloat16*)C)[(size_t)m * D_MODEL + n] = __float2bfloat16(val);
        else
          ((float*)C)[(size_t)m * D_MODEL + n] = val;
      }
    }
  }
}

// ---------------------------------------------------------------------------
// Transpose V per head: vpr[t][h*64+d] (row-major proj) -> vt[h][d][t]
// ---------------------------------------------------------------------------
__global__ __launch_bounds__(256) void transpose_v(const __hip_bfloat16* __restrict__ vpr,
                                                   __hip_bfloat16* __restrict__ vt) {
  __shared__ __align__(16) __hip_bfloat16 tile[64][72];
  const int t0 = blockIdx.x * 64;
  const int h = blockIdx.y;
  const int tid = threadIdx.x;
  const short* plane = (const short*)vpr;
  short* oplane = (short*)(vt + (size_t)h * HEAD_DIM * VT_STRIDE);

  for (int idx = tid; idx < 64 * 8; idx += 256) {
    const int row = idx >> 3, ch = idx & 7;
    const int t = t0 + row;
    short8 v = {0, 0, 0, 0, 0, 0, 0, 0};
    if (t < T_SEQ) v = *(const short8*)(plane + (size_t)t * D_MODEL + h * 64 + ch * 8);
    *(short8*)&tile[row][ch * 8] = v;
  }
  __syncthreads();
  for (int idx = tid; idx < 64 * 8; idx += 256) {
    const int d = idx >> 3, ch = idx & 7;
    if (t0 + ch * 8 < VT_STRIDE) {
      short8 v;
#pragma unroll
      for (int i = 0; i < 8; i++) v[i] = *(const short*)&tile[ch * 8 + i][d];
      *(short8*)(oplane + (size_t)d * VT_STRIDE + t0 + ch * 8) = v;
    }
  }
}

// ---------------------------------------------------------------------------
// Flash attention with relative position, bf16 MFMA 16x16x32.
// S[t][s] = q[t].k[s] + q[t+1].Er[s]  ==  [Q|Q+1](64x128) @ [K|Er](64x128)^T
// Q fragments loaded once from global into registers (loop-invariant).
// LDS strides chosen so hot ds_read_b128 bank-groups are (3n+q)%8 -> 2-way.
// ---------------------------------------------------------------------------
__global__ __launch_bounds__(256) void flash_attn(
    const __hip_bfloat16* __restrict__ qpr, const __hip_bfloat16* __restrict__ kpr,
    const float* __restrict__ Er, const __hip_bfloat16* __restrict__ vt,
    __hip_bfloat16* __restrict__ ctx) {
  constexpr int LKQ = 152;  // 128 + 24 pad -> 304B rows, (3n+q)%8 banks
  constexpr int LVP = 88;   // 64 + 24 pad -> 176B rows
  __shared__ __align__(16) __hip_bfloat16 Ks[64][LKQ];
  __shared__ __align__(16) __hip_bfloat16 Vt[64][LVP];
  __shared__ __align__(16) __hip_bfloat16 Ps[64][LVP];

  const int tid = threadIdx.x;
  const int h = blockIdx.y;
  // balanced qt pairing: 0,32,1,31,2,30,... so adjacent blocks sum ~equal work
  const int bx = blockIdx.x;
  const int qt = (bx & 1) ? (32 - (bx >> 1)) : (bx >> 1);

  const int wave = tid >> 6;
  const int lane = tid & 63;
  const int col = lane & 15;
  const int quad = lane >> 4;

  const short* qplane = (const short*)qpr;
  const short* kplane = (const short*)kpr;
  const short* vplane = (const short*)(vt + (size_t)h * HEAD_DIM * VT_STRIDE);

  // ---- Q fragments: loop-invariant, straight from global into registers.
  // Qaug[m][c]: c<64 -> q[m][c]; c>=64 -> q[m+1][c-64] (zero if m+1>=T)
  const int mrow = qt * 64 + wave * 16 + col;
  const int mc0 = min(mrow, T_SEQ - 1);
  const int mc1 = min(mrow + 1, T_SEQ - 1);
  const bool hiz = (mrow + 1 >= T_SEQ);
  short8 aq[4];
#pragma unroll
  for (int kc = 0; kc < 4; kc++) {
    const size_t off = (kc < 2)
                           ? ((size_t)mc0 * D_MODEL + h * 64 + kc * 32 + quad * 8)
                           : ((size_t)mc1 * D_MODEL + h * 64 + (kc - 2) * 32 + quad * 8);
    short8 v = *(const short8*)(qplane + off);
    if (kc >= 2 && hiz) v = (short8){0, 0, 0, 0, 0, 0, 0, 0};
    aq[kc] = v;
  }

  floatx4 o[4];
  float m_i[4], l_i[4];
#pragma unroll
  for (int i = 0; i < 4; i++) {
    o[i] = (floatx4){0.f, 0.f, 0.f, 0.f};
    m_i[i] = -INFINITY;
    l_i[i] = 0.f;
  }

  for (int j = 0; j <= qt; ++j) {
    if (j) __syncthreads();
    const int s0 = j * 64;
    // ---- stage K|Er tile (64 x 128) and V^T tile (64 x 64)
    for (int idx = tid; idx < 64 * 16; idx += 256) {
      const int row = idx >> 4, ch = idx & 15;
      const int s = s0 + row;
      short8 v = {0, 0, 0, 0, 0, 0, 0, 0};
      if (s < T_SEQ) {
        if (ch < 8)
          v = *(const short8*)(kplane + (size_t)s * D_MODEL + h * 64 + ch * 8);
        else
          v = cvt8_bf16(Er + (size_t)s * HEAD_DIM + (ch - 8) * 8);
      }
      *(short8*)&Ks[row][ch * 8] = v;
    }
    for (int idx = tid; idx < 64 * 8; idx += 256) {
      const int d = idx >> 3, ch = idx & 7;
      short8 v = {0, 0, 0, 0, 0, 0, 0, 0};
      if (s0 + ch * 8 + 8 <= VT_STRIDE)
        v = *(const short8*)(vplane + (size_t)d * VT_STRIDE + s0 + ch * 8);
      *(short8*)&Vt[d][ch * 8] = v;
    }
    __syncthreads();

    // ---- S = Qaug @ Kaug^T  (wave strip 16 x 64, K=128)
    floatx4 s[4];
#pragma unroll
    for (int ct = 0; ct < 4; ct++) {
      floatx4 c = {0.f, 0.f, 0.f, 0.f};
#pragma unroll
      for (int kc = 0; kc < 4; kc++) {
        short8 b = *(const short8*)&Ks[ct * 16 + col][kc * 32 + quad * 8];
        c = __builtin_amdgcn_mfma_f32_16x16x32_bf16(aq[kc], b, c, 0, 0, 0);
      }
      s[ct] = c;
    }

    // ---- causal mask (diagonal tile only)
    if (j == qt) {
      const int trow = qt * 64 + wave * 16 + quad * 4;
#pragma unroll
      for (int ct = 0; ct < 4; ct++) {
        const int scol = s0 + ct * 16 + col;
#pragma unroll
        for (int r = 0; r < 4; r++)
          if (scol > trow + r) s[ct][r] = -INFINITY;
      }
    }

    // ---- online softmax (row r lives in 16 lanes of this quad-group)
#pragma unroll
    for (int r = 0; r < 4; r++) {
      float mx = fmaxf(fmaxf(s[0][r], s[1][r]), fmaxf(s[2][r], s[3][r]));
#pragma unroll
      for (int off = 1; off <= 8; off <<= 1) mx = fmaxf(mx, __shfl_xor(mx, off, 64));
      const float mnew = fmaxf(m_i[r], mx);
      const float alpha = __expf((m_i[r] - mnew) * 0.125f);
      m_i[r] = mnew;
      float rs = 0.f;
#pragma unroll
      for (int ct = 0; ct < 4; ct++) {
        const float p = __expf((s[ct][r] - mnew) * 0.125f);
        s[ct][r] = p;
        rs += p;
      }
#pragma unroll
      for (int off = 1; off <= 8; off <<= 1) rs += __shfl_xor(rs, off, 64);
      l_i[r] = l_i[r] * alpha + rs;
#pragma unroll
      for (int nt = 0; nt < 4; nt++) o[nt][r] *= alpha;
    }

    // ---- P (C-layout) -> LDS -> A-layout for PV
#pragma unroll
    for (int ct = 0; ct < 4; ct++)
#pragma unroll
      for (int r = 0; r < 4; r++)
        Ps[wave * 16 + quad * 4 + r][ct * 16 + col] = __float2bfloat16(s[ct][r]);
    __syncthreads();

    short8 pa[2];
#pragma unroll
    for (int kc = 0; kc < 2; kc++)
      pa[kc] = *(const short8*)&Ps[wave * 16 + col][kc * 32 + quad * 8];
#pragma unroll
    for (int nt = 0; nt < 4; nt++)
#pragma unroll
      for (int kc = 0; kc < 2; kc++) {
        short8 b = *(const short8*)&Vt[nt * 16 + col][kc * 32 + quad * 8];
        o[nt] = __builtin_amdgcn_mfma_f32_16x16x32_bf16(pa[kc], b, o[nt], 0, 0, 0);
      }
  }

  // ---- epilogue: normalize, store bf16 ctx[t][h*64 + d]
  const int trow = qt * 64 + wave * 16 + quad * 4;
#pragma unroll
  for (int r = 0; r < 4; r++) {
    const int t = trow + r;
    if (t < T_SEQ) {
      const float iv = 1.0f / l_i[r];
#pragma unroll
      for (int nt = 0; nt < 4; nt++)
        ctx[(size_t)t * D_MODEL + h * 64 + nt * 16 + col] =
            __float2bfloat16(o[nt][r] * iv);
    }
  }
}

// ---------------------------------------------------------------------------
extern "C" void kernel_launch(void* const* d_in, const int* in_sizes, int n_in,
                              void* d_out, int out_size, void* d_ws, size_t ws_size,
                              hipStream_t stream) {
  const float* q = (const float*)d_in[0];
  const float* k = (const float*)d_in[1];
  const float* v = (const float*)d_in[2];
  const float* Wq_w = (const float*)d_in[4];
  const float* Wq_b = (const float*)d_in[5];
  const float* Wk_w = (const float*)d_in[6];
  const float* Wk_b = (const float*)d_in[7];
  const float* Wv_w = (const float*)d_in[8];
  const float* Wv_b = (const float*)d_in[9];
  const float* Er = (const float*)d_in[10];
  const float* Wo_w = (const float*)d_in[11];
  const float* Wo_b = (const float*)d_in[12];
  float* out = (float*)d_out;

  // ---- workspace carve-up (fits in 33.57 MB proven budget)
  char* ws = (char*)d_ws;
  const size_t sz_plane = (size_t)T_SEQ * D_MODEL * 2;  // 4,196,352 B
  const size_t sz_w = (size_t)D_MODEL * D_MODEL * 2;    // 2,097,152 B
  __hip_bfloat16* qbf = (__hip_bfloat16*)ws;                  // dead after QKV GEMM
  __hip_bfloat16* kbf = (__hip_bfloat16*)(ws + sz_plane);     // dead after QKV GEMM
  __hip_bfloat16* vbf = (__hip_bfloat16*)(ws + 2 * sz_plane); // dead after QKV GEMM
  char* wbase = ws + 3 * sz_plane;
  __hip_bfloat16* wqb = (__hip_bfloat16*)(wbase);
  __hip_bfloat16* wkb = (__hip_bfloat16*)(wbase + sz_w);
  __hip_bfloat16* wvb = (__hip_bfloat16*)(wbase + 2 * sz_w);
  __hip_bfloat16* wob = (__hip_bfloat16*)(wbase + 3 * sz_w);
  char* pbase = wbase + 4 * sz_w;
  __hip_bfloat16* qpr = (__hip_bfloat16*)(pbase);
  __hip_bfloat16* kpr = (__hip_bfloat16*)(pbase + sz_plane);
  __hip_bfloat16* vpr = (__hip_bfloat16*)(pbase + 2 * sz_plane);
  // overlays on dead qbf/kbf/vbf region (12.58 MB): vt (4.21 MB) + ctx (4.2 MB)
  __hip_bfloat16* vt = (__hip_bfloat16*)ws;
  __hip_bfloat16* ctxb =
      (__hip_bfloat16*)(ws + (size_t)N_HEAD * HEAD_DIM * VT_STRIDE * 2);

  const dim3 blk(256);
  const int n_in_elems = T_SEQ * D_MODEL;  // 2,098,176 (mult of 8)
  const int n_w_elems = D_MODEL * D_MODEL;

  cast_bf16x<<<dim3((n_in_elems + 2047) / 2048, 3), blk, 0, stream>>>(
      q, k, v, q, qbf, kbf, vbf, qbf, n_in_elems);
  cast_bf16x<<<dim3(n_w_elems / 2048, 4), blk, 0, stream>>>(
      Wq_w, Wk_w, Wv_w, Wo_w, wqb, wkb, wvb, wob, n_w_elems);

  // fused QKV projections (bf16 row-major outputs)
  mfma_gemm<1><<<dim3(8, 17, 3), blk, 0, stream>>>(qbf, kbf, vbf, wqb, wkb, wvb, Wq_b,
                                                   Wk_b, Wv_b, qpr, kpr, vpr, T_SEQ);

  transpose_v<<<dim3(33, N_HEAD), blk, 0, stream>>>(vpr, vt);

  flash_attn<<<dim3(33, N_HEAD), blk, 0, stream>>>(qpr, kpr, Er, vt, ctxb);

  // output projection (fp32 out)
  mfma_gemm<0><<<dim3(8, 17, 1), blk, 0, stream>>>(ctxb, ctxb, ctxb, wob, wob, wob,
                                                   Wo_b, Wo_b, Wo_b, out, out, out,
                                                   T_SEQ);
}

// Round 4
// 243.974 us; speedup vs baseline: 20.5406x; 1.3681x over previous
//
#include <hip/hip_runtime.h>
#include <hip/hip_bf16.h>
#include <math.h>

constexpr int T_SEQ = 2049;
constexpr int D_MODEL = 1024;
constexpr int N_HEAD = 16;
constexpr int HEAD_DIM = 64;
constexpr int VT_STRIDE = 2112;  // 2048+64: all V tile reads in-bounds, zero-padded

typedef __attribute__((ext_vector_type(8))) short short8;
typedef __attribute__((ext_vector_type(4))) short short4v;
typedef __attribute__((ext_vector_type(4))) float floatx4;

// async global->LDS, 16B per lane; LDS dest = wave-uniform base + lane*16
__device__ inline void load_lds16(const void* g, void* l) {
  __builtin_amdgcn_global_load_lds(
      (const __attribute__((address_space(1))) unsigned int*)g,
      (__attribute__((address_space(3))) unsigned int*)l, 16, 0, 0);
}

__device__ inline short8 cvt8_bf16(const float* p) {
  float4 a = *(const float4*)p, b = *(const float4*)(p + 4);
  __hip_bfloat16 t[8] = {__float2bfloat16(a.x), __float2bfloat16(a.y),
                         __float2bfloat16(a.z), __float2bfloat16(a.w),
                         __float2bfloat16(b.x), __float2bfloat16(b.y),
                         __float2bfloat16(b.z), __float2bfloat16(b.w)};
  return *(const short8*)t;
}

// ---------------------------------------------------------------------------
// batched fp32 -> bf16 cast (z selects tensor), 8 elems/thread
// ---------------------------------------------------------------------------
__global__ __launch_bounds__(256) void cast_bf16x(
    const float* __restrict__ i0, const float* __restrict__ i1,
    const float* __restrict__ i2, const float* __restrict__ i3,
    __hip_bfloat16* __restrict__ o0, __hip_bfloat16* __restrict__ o1,
    __hip_bfloat16* __restrict__ o2, __hip_bfloat16* __restrict__ o3, int n) {
  const int z = blockIdx.y;
  const float* in = z == 0 ? i0 : z == 1 ? i1 : z == 2 ? i2 : i3;
  __hip_bfloat16* out = z == 0 ? o0 : z == 1 ? o1 : z == 2 ? o2 : o3;
  const int i = (blockIdx.x * 256 + threadIdx.x) * 8;
  if (i + 8 > n) return;
  *(short8*)(out + i) = cvt8_bf16(in + i);
}

__global__ __launch_bounds__(256) void cast_bf16_one(const float* __restrict__ in,
                                                     __hip_bfloat16* __restrict__ out,
                                                     int n) {
  const int i = (blockIdx.x * 256 + threadIdx.x) * 8;
  if (i + 8 > n) return;
  *(short8*)(out + i) = cvt8_bf16(in + i);
}

// ---------------------------------------------------------------------------
// bf16 MFMA GEMM: C[M x 1024] = A[M x 1024] @ W[1024 x 1024]^T + bias
// 128x128 tile, BK=32, 256 threads. XOR source-chunk swizzle for staging.
// OUTK: 0 -> fp32 row-major; 2 -> QKV mode (z<2 bf16 head-major, z==2 bf16 row)
// ---------------------------------------------------------------------------
template <int OUTK>
__global__ __launch_bounds__(256) void mfma_gemm(
    const __hip_bfloat16* __restrict__ A0, const __hip_bfloat16* __restrict__ A1,
    const __hip_bfloat16* __restrict__ A2, const __hip_bfloat16* __restrict__ W0,
    const __hip_bfloat16* __restrict__ W1, const __hip_bfloat16* __restrict__ W2,
    const float* __restrict__ bias0, const float* __restrict__ bias1,
    const float* __restrict__ bias2, void* C0, void* C1, void* C2, int M) {
  constexpr int K = D_MODEL;
  __shared__ __align__(16) __hip_bfloat16 As[128 * 32];
  __shared__ __align__(16) __hip_bfloat16 Bs[128 * 32];

  const int z = blockIdx.z;
  const short* A = (const short*)(z == 0 ? A0 : z == 1 ? A1 : A2);
  const short* W = (const short*)(z == 0 ? W0 : z == 1 ? W1 : W2);
  const float* bias = z == 0 ? bias0 : z == 1 ? bias1 : bias2;
  void* C = z == 0 ? C0 : z == 1 ? C1 : C2;

  const int tid = threadIdx.x;
  const int wave = tid >> 6, lane = tid & 63;
  const int col = lane & 15, quad = lane >> 4;
  const int wm = wave >> 1, wn = wave & 1;
  const int m0 = blockIdx.y * 128, n0 = blockIdx.x * 128;

  const int sr = lane >> 2;
  const int ss = lane & 3;
  const int sch = ss ^ ((sr >> 1) & 3);

  floatx4 acc[4][4];
#pragma unroll
  for (int i = 0; i < 4; i++)
#pragma unroll
    for (int j = 0; j < 4; j++) acc[i][j] = (floatx4){0.f, 0.f, 0.f, 0.f};

  for (int k0 = 0; k0 < K; k0 += 32) {
    if (k0) __syncthreads();
#pragma unroll
    for (int i = 0; i < 2; i++) {
      const int rb = wave * 32 + i * 16;
      const int am = min(m0 + rb + sr, M - 1);
      load_lds16(A + (size_t)am * K + k0 + sch * 8, (char*)As + rb * 64);
      const int bn = n0 + rb + sr;
      load_lds16(W + (size_t)bn * K + k0 + sch * 8, (char*)Bs + rb * 64);
    }
    __syncthreads();

    short8 af[4], bf[4];
#pragma unroll
    for (int t = 0; t < 4; t++) {
      const int ra = wm * 64 + t * 16 + col;
      af[t] = *(const short8*)(As + ra * 32 + (quad ^ ((ra >> 1) & 3)) * 8);
      const int rb = wn * 64 + t * 16 + col;
      bf[t] = *(const short8*)(Bs + rb * 32 + (quad ^ ((rb >> 1) & 3)) * 8);
    }
#pragma unroll
    for (int mt = 0; mt < 4; mt++)
#pragma unroll
      for (int nt = 0; nt < 4; nt++)
        acc[mt][nt] =
            __builtin_amdgcn_mfma_f32_16x16x32_bf16(af[mt], bf[nt], acc[mt][nt], 0, 0, 0);
  }

#pragma unroll
  for (int mt = 0; mt < 4; mt++) {
#pragma unroll
    for (int r = 0; r < 4; r++) {
      const int m = m0 + wm * 64 + mt * 16 + quad * 4 + r;
      if (m >= M) continue;
#pragma unroll
      for (int nt = 0; nt < 4; nt++) {
        const int n = n0 + wn * 64 + nt * 16 + col;
        const float val = acc[mt][nt][r] + bias[n];
        if (OUTK == 0) {
          ((float*)C)[(size_t)m * D_MODEL + n] = val;
        } else {
          if (z < 2) {  // head-major [h][t][hd] for Q,K
            const int h = n >> 6, hd = n & 63;
            ((__hip_bfloat16*)C)[((size_t)h * T_SEQ + m) * HEAD_DIM + hd] =
                __float2bfloat16(val);
          } else {  // row-major for V (transpose kernel reads this)
            ((__hip_bfloat16*)C)[(size_t)m * D_MODEL + n] = __float2bfloat16(val);
          }
        }
      }
    }
  }
}

// ---------------------------------------------------------------------------
// Transpose V per head: vpr[t][h*64+d] (row-major) -> vt[h][d][t], t-pad zeroed
// ---------------------------------------------------------------------------
__global__ __launch_bounds__(256) void transpose_v(const __hip_bfloat16* __restrict__ vpr,
                                                   __hip_bfloat16* __restrict__ vt) {
  __shared__ __align__(16) __hip_bfloat16 tile[64][72];
  const int t0 = blockIdx.x * 64;
  const int h = blockIdx.y;
  const int tid = threadIdx.x;
  const short* plane = (const short*)vpr;
  short* oplane = (short*)(vt + (size_t)h * HEAD_DIM * VT_STRIDE);

  for (int idx = tid; idx < 64 * 8; idx += 256) {
    const int row = idx >> 3, ch = idx & 7;
    const int t = t0 + row;
    short8 v = {0, 0, 0, 0, 0, 0, 0, 0};
    if (t < T_SEQ) v = *(const short8*)(plane + (size_t)t * D_MODEL + h * 64 + ch * 8);
    *(short8*)&tile[row][ch * 8] = v;
  }
  __syncthreads();
  for (int idx = tid; idx < 64 * 8; idx += 256) {
    const int d = idx >> 3, ch = idx & 7;
    short8 v;
#pragma unroll
    for (int i = 0; i < 8; i++) v[i] = *(const short*)&tile[ch * 8 + i][d];
    *(short8*)(oplane + (size_t)d * VT_STRIDE + t0 + ch * 8) = v;
  }
}

// ---------------------------------------------------------------------------
// Flash attention v2: S^T MFMA trick.
//  S^T = Kaug(64x128) @ Qaug^T   -> lane holds S[t=col][s=quad*4+r]
//  -> per-lane scalar softmax state, 2-shuffle row reduce
//  -> P re-laid via per-wave-private frag-major LDS (no barrier)
//  -> PV with V^T staged via swizzled global_load_lds
// BM=128 (8 waves x 16 t-rows), BN=64, double-buffered, 1 barrier/iter.
// ---------------------------------------------------------------------------
__global__ __launch_bounds__(512, 4) void flash_attn(
    const __hip_bfloat16* __restrict__ qh, const __hip_bfloat16* __restrict__ kh,
    const __hip_bfloat16* __restrict__ er, const __hip_bfloat16* __restrict__ vt,
    __hip_bfloat16* __restrict__ ctx) {
  __shared__ __align__(16) __hip_bfloat16 Ks[2][64 * 128];  // [s][kaug] swizzled
  __shared__ __align__(16) __hip_bfloat16 Vs[2][64 * 64];   // [d][s] swizzled
  __shared__ __align__(16) __hip_bfloat16 Ps[8][1024];      // per-wave frag-major

  const int tid = threadIdx.x;
  const int h = blockIdx.y;
  const int bx = blockIdx.x;
  const int qt = (bx & 1) ? (16 - (bx >> 1)) : (bx >> 1);  // 0,16,1,15,...,8
  const int tq0 = qt * 128;

  const int wave = tid >> 6;
  const int lane = tid & 63;
  const int col = lane & 15;
  const int quad = lane >> 4;

  const short* qplane = (const short*)(qh + (size_t)h * T_SEQ * HEAD_DIM);
  const short* kplane = (const short*)(kh + (size_t)h * T_SEQ * HEAD_DIM);
  const short* eplane = (const short*)er;
  const short* vplane = (const short*)(vt + (size_t)h * HEAD_DIM * VT_STRIDE);

  // ---- Q fragments (B-operand): lane holds Qaug[t = tq0+wave*16+col][k]
  const int t_abs = tq0 + wave * 16 + col;
  const int tload = min(t_abs, T_SEQ - 1);
  const bool hiz = (t_abs >= T_SEQ - 1);  // q[t+1] is zero (or t garbage)
  short8 aq[4];
#pragma unroll
  for (int kc = 0; kc < 4; kc++) {
    short8 v = *(const short8*)(qplane + (size_t)tload * 64 + kc * 32 + quad * 8);
    if (kc >= 2 && hiz) v = (short8){0, 0, 0, 0, 0, 0, 0, 0};
    aq[kc] = v;
  }

  floatx4 o[4];
  float m_i = -INFINITY, l_i = 0.f;
#pragma unroll
  for (int i = 0; i < 4; i++) o[i] = (floatx4){0.f, 0.f, 0.f, 0.f};

  const int jmax = min(tq0 + 127, T_SEQ - 1) >> 6;  // last s-tile index
  const int tstrip = tq0 + wave * 16;               // first t of this wave
  __hip_bfloat16* psw = &Ps[wave][0];

  // ---- staging lambda-ish (macro-expanded twice) ----
  // K|Er tile: 16 KB, 16 instrs (2/wave). rows r=4i+(lane>>4), slot=lane&15
  // V^T tile: 8 KB, 8 instrs (1/wave).  rows d=wave*8+(lane>>3), slot=lane&7
#define STAGE_TILE(JJ, BUF)                                                        \
  {                                                                                \
    const int s0_ = (JJ) * 64;                                                     \
    _Pragma("unroll") for (int ii = 0; ii < 2; ii++) {                             \
      const int i_ = wave * 2 + ii;                                                \
      const int r_ = i_ * 4 + (lane >> 4);                                         \
      const int sl_ = lane & 15;                                                   \
      const int g_ = (sl_ & 8) | ((sl_ ^ (r_ & 7)) & 7);                           \
      const int s_ = min(s0_ + r_, T_SEQ - 1);                                     \
      const short* src_ = (g_ < 8) ? (kplane + (size_t)s_ * 64 + g_ * 8)           \
                                   : (eplane + (size_t)s_ * 64 + (g_ - 8) * 8);    \
      load_lds16(src_, (char*)&Ks[BUF][0] + i_ * 1024);                            \
    }                                                                              \
    {                                                                              \
      const int d_ = wave * 8 + (lane >> 3);                                       \
      const int sl_ = lane & 7;                                                    \
      const int g_ = sl_ ^ (d_ & 7);                                               \
      load_lds16(vplane + (size_t)d_ * VT_STRIDE + s0_ + g_ * 8,                   \
                 (char*)&Vs[BUF][0] + wave * 1024);                                \
    }                                                                              \
  }

  STAGE_TILE(0, 0)
  int buf = 0;

  for (int j = 0; j <= jmax; ++j, buf ^= 1) {
    __syncthreads();  // drains stage(j) vmcnt; all waves done with buf^1 reads
    if (j < jmax) STAGE_TILE(j + 1, buf ^ 1)

    const int s0 = j * 64;
    if (s0 > tstrip + 15) continue;  // whole strip masked: staging+barrier only

    const __hip_bfloat16* ks = &Ks[buf][0];
    const __hip_bfloat16* vs = &Vs[buf][0];

    // ---- S^T: lane gets S[t=col][s = st*16+quad*4+r]
    floatx4 sacc[4];
#pragma unroll
    for (int st = 0; st < 4; st++) {
      floatx4 c = {0.f, 0.f, 0.f, 0.f};
      const int row = st * 16 + col;
#pragma unroll
      for (int kc = 0; kc < 4; kc++) {
        const int ch = kc * 4 + quad;
        const int slot = (ch & 8) | ((ch ^ (row & 7)) & 7);
        short8 ka = *(const short8*)(ks + row * 128 + slot * 8);
        c = __builtin_amdgcn_mfma_f32_16x16x32_bf16(ka, aq[kc], c, 0, 0, 0);
      }
      sacc[st] = c;
    }

    // ---- causal mask (only when tile straddles the diagonal)
    if (s0 + 63 > tstrip) {
#pragma unroll
      for (int st = 0; st < 4; st++) {
        const int sbase = s0 + st * 16 + quad * 4;
#pragma unroll
        for (int r = 0; r < 4; r++)
          if (sbase + r > t_abs) sacc[st][r] = -INFINITY;
      }
    }

    // ---- online softmax: per-lane scalar state (t = col), reduce over quads
    float mx = -INFINITY;
#pragma unroll
    for (int st = 0; st < 4; st++)
#pragma unroll
      for (int r = 0; r < 4; r++) mx = fmaxf(mx, sacc[st][r]);
    mx = fmaxf(mx, __shfl_xor(mx, 16, 64));
    mx = fmaxf(mx, __shfl_xor(mx, 32, 64));
    const float mnew = fmaxf(m_i, mx);
    const float alpha = __expf((m_i - mnew) * 0.125f);
    m_i = mnew;
    float rs = 0.f;
#pragma unroll
    for (int st = 0; st < 4; st++)
#pragma unroll
      for (int r = 0; r < 4; r++) {
        const float p = __expf((sacc[st][r] - mnew) * 0.125f);
        sacc[st][r] = p;
        rs += p;
      }
    rs += __shfl_xor(rs, 16, 64);
    rs += __shfl_xor(rs, 32, 64);
    l_i = l_i * alpha + rs;

    // ---- rescale O: alpha lives at lane col=t_local; O rows are quad*4+r
    float a_r[4];
#pragma unroll
    for (int r = 0; r < 4; r++) a_r[r] = __shfl(alpha, quad * 4 + r, 64);
#pragma unroll
    for (int nt = 0; nt < 4; nt++)
#pragma unroll
      for (int r = 0; r < 4; r++) o[nt][r] *= a_r[r];

    // ---- P -> per-wave frag-major LDS (no barrier: wave-private region)
    // write: elem P[t=col][s=st*16+quad*4+r] -> slot kcA=st>>1,
    //        quadA=(st&1)*2+(quad>>1), j=(quad&1)*4+r
#pragma unroll
    for (int st = 0; st < 4; st++) {
      __hip_bfloat16 pb[4];
#pragma unroll
      for (int r = 0; r < 4; r++) pb[r] = __float2bfloat16(sacc[st][r]);
      const int kcA = st >> 1;
      const int quadA = (st & 1) * 2 + (quad >> 1);
      const int off = ((kcA * 4 + quadA) * 16 + col) * 8 + (quad & 1) * 4;
      *(short4v*)(psw + off) = *(const short4v*)pb;
    }
    // read: pa[kc] = P[t=col][s = kc*32+quad*8+j]
    short8 pa[2];
#pragma unroll
    for (int kc = 0; kc < 2; kc++)
      pa[kc] = *(const short8*)(psw + ((kc * 4 + quad) * 16 + col) * 8);

    // ---- PV: A = P-frag, B = V^T-frag
#pragma unroll
    for (int nt = 0; nt < 4; nt++) {
      const int row = nt * 16 + col;
#pragma unroll
      for (int kc = 0; kc < 2; kc++) {
        const int slot = (kc * 4 + quad) ^ (row & 7);
        short8 vb = *(const short8*)(vs + row * 64 + slot * 8);
        o[nt] = __builtin_amdgcn_mfma_f32_16x16x32_bf16(pa[kc], vb, o[nt], 0, 0, 0);
      }
    }
  }

  // ---- epilogue: O rows t = tstrip + quad*4 + r; l_i lives at lane col=t_local
  const float linv = 1.0f / l_i;
  float linv_r[4];
#pragma unroll
  for (int r = 0; r < 4; r++) linv_r[r] = __shfl(linv, quad * 4 + r, 64);
#pragma unroll
  for (int r = 0; r < 4; r++) {
    const int t = tstrip + quad * 4 + r;
    if (t < T_SEQ) {
#pragma unroll
      for (int nt = 0; nt < 4; nt++)
        ctx[(size_t)t * D_MODEL + h * 64 + nt * 16 + col] =
            __float2bfloat16(o[nt][r] * linv_r[r]);
    }
  }
}

// ---------------------------------------------------------------------------
extern "C" void kernel_launch(void* const* d_in, const int* in_sizes, int n_in,
                              void* d_out, int out_size, void* d_ws, size_t ws_size,
                              hipStream_t stream) {
  const float* q = (const float*)d_in[0];
  const float* k = (const float*)d_in[1];
  const float* v = (const float*)d_in[2];
  const float* Wq_w = (const float*)d_in[4];
  const float* Wq_b = (const float*)d_in[5];
  const float* Wk_w = (const float*)d_in[6];
  const float* Wk_b = (const float*)d_in[7];
  const float* Wv_w = (const float*)d_in[8];
  const float* Wv_b = (const float*)d_in[9];
  const float* Er = (const float*)d_in[10];
  const float* Wo_w = (const float*)d_in[11];
  const float* Wo_b = (const float*)d_in[12];
  float* out = (float*)d_out;

  // ---- workspace carve-up (33.57 MB peak, same as proven round-1 budget)
  char* ws = (char*)d_ws;
  const size_t sz_plane = (size_t)T_SEQ * D_MODEL * 2;  // 4,196,352 B
  const size_t sz_w = (size_t)D_MODEL * D_MODEL * 2;    // 2,097,152 B
  __hip_bfloat16* qbf = (__hip_bfloat16*)ws;
  __hip_bfloat16* kbf = (__hip_bfloat16*)(ws + sz_plane);
  __hip_bfloat16* vbf = (__hip_bfloat16*)(ws + 2 * sz_plane);
  char* wbase = ws + 3 * sz_plane;
  __hip_bfloat16* wqb = (__hip_bfloat16*)(wbase);
  __hip_bfloat16* wkb = (__hip_bfloat16*)(wbase + sz_w);
  __hip_bfloat16* wvb = (__hip_bfloat16*)(wbase + 2 * sz_w);
  __hip_bfloat16* wob = (__hip_bfloat16*)(wbase + 3 * sz_w);
  char* pbase = wbase + 4 * sz_w;
  __hip_bfloat16* qpr = (__hip_bfloat16*)(pbase);               // head-major
  __hip_bfloat16* kpr = (__hip_bfloat16*)(pbase + sz_plane);    // head-major
  __hip_bfloat16* vpr = (__hip_bfloat16*)(pbase + 2 * sz_plane);// row-major
  // overlays on dead qbf/kbf/vbf region (12.58 MB), used only after QKV GEMM:
  const size_t sz_vt = (size_t)N_HEAD * HEAD_DIM * VT_STRIDE * 2;  // 4,325,376
  __hip_bfloat16* vt = (__hip_bfloat16*)ws;
  __hip_bfloat16* ctxb = (__hip_bfloat16*)(ws + sz_vt);
  __hip_bfloat16* er_bf = (__hip_bfloat16*)(ws + sz_vt + sz_plane);

  const dim3 blk(256);
  const int n_in_elems = T_SEQ * D_MODEL;
  const int n_w_elems = D_MODEL * D_MODEL;
  const int n_er = T_SEQ * HEAD_DIM;  // 131,136 (mult of 8)

  cast_bf16x<<<dim3((n_in_elems + 2047) / 2048, 3), blk, 0, stream>>>(
      q, k, v, q, qbf, kbf, vbf, qbf, n_in_elems);
  cast_bf16x<<<dim3(n_w_elems / 2048, 4), blk, 0, stream>>>(
      Wq_w, Wk_w, Wv_w, Wo_w, wqb, wkb, wvb, wob, n_w_elems);

  // fused QKV projections: Q,K head-major bf16; V row-major bf16
  mfma_gemm<2><<<dim3(8, 17, 3), blk, 0, stream>>>(qbf, kbf, vbf, wqb, wkb, wvb, Wq_b,
                                                   Wk_b, Wv_b, qpr, kpr, vpr, T_SEQ);

  // overlay region now safe to write
  cast_bf16_one<<<dim3((n_er + 2047) / 2048), blk, 0, stream>>>(Er, er_bf, n_er);
  transpose_v<<<dim3(33, N_HEAD), blk, 0, stream>>>(vpr, vt);

  flash_attn<<<dim3(17, N_HEAD), dim3(512), 0, stream>>>(qpr, kpr, er_bf, vt, ctxb);

  // output projection (fp32 out)
  mfma_gemm<0><<<dim3(8, 17, 1), blk, 0, stream>>>(ctxb, ctxb, ctxb, wob, wob, wob,
                                                   Wo_b, Wo_b, Wo_b, out, out, out,
                                                   T_SEQ);
}

// Round 6
// 215.326 us; speedup vs baseline: 23.2735x; 1.1330x over previous
//
#include <hip/hip_runtime.h>
#include <hip/hip_bf16.h>
#include <math.h>

constexpr int T_SEQ = 2049;
constexpr int D_MODEL = 1024;
constexpr int N_HEAD = 16;
constexpr int HEAD_DIM = 64;
constexpr int VT_STRIDE = 2112;  // 2048+64: all V tile reads in-bounds, zero-padded
constexpr int T1_ROWS = 1152;    // rows 1024..2175 for split-1 partial buffers

typedef __attribute__((ext_vector_type(8))) short short8;
typedef __attribute__((ext_vector_type(4))) short short4v;
typedef __attribute__((ext_vector_type(4))) float floatx4;

// async global->LDS, 16B per lane; LDS dest = wave-uniform base + lane*16
__device__ inline void load_lds16(const void* g, void* l) {
  __builtin_amdgcn_global_load_lds(
      (const __attribute__((address_space(1))) unsigned int*)g,
      (__attribute__((address_space(3))) unsigned int*)l, 16, 0, 0);
}

__device__ inline short8 cvt8_bf16(const float* p) {
  float4 a = *(const float4*)p, b = *(const float4*)(p + 4);
  __hip_bfloat16 t[8] = {__float2bfloat16(a.x), __float2bfloat16(a.y),
                         __float2bfloat16(a.z), __float2bfloat16(a.w),
                         __float2bfloat16(b.x), __float2bfloat16(b.y),
                         __float2bfloat16(b.z), __float2bfloat16(b.w)};
  return *(const short8*)t;
}

__device__ inline float bf2f(__hip_bfloat16 x) { return __bfloat162float(x); }

// ---------------------------------------------------------------------------
// batched fp32 -> bf16 cast (z selects tensor), 8 elems/thread
// ---------------------------------------------------------------------------
__global__ __launch_bounds__(256) void cast_bf16x(
    const float* __restrict__ i0, const float* __restrict__ i1,
    const float* __restrict__ i2, const float* __restrict__ i3,
    __hip_bfloat16* __restrict__ o0, __hip_bfloat16* __restrict__ o1,
    __hip_bfloat16* __restrict__ o2, __hip_bfloat16* __restrict__ o3, int n) {
  const int z = blockIdx.y;
  const float* in = z == 0 ? i0 : z == 1 ? i1 : z == 2 ? i2 : i3;
  __hip_bfloat16* out = z == 0 ? o0 : z == 1 ? o1 : z == 2 ? o2 : o3;
  const int i = (blockIdx.x * 256 + threadIdx.x) * 8;
  if (i + 8 > n) return;
  *(short8*)(out + i) = cvt8_bf16(in + i);
}

__global__ __launch_bounds__(256) void cast_bf16_one(const float* __restrict__ in,
                                                     __hip_bfloat16* __restrict__ out,
                                                     int n) {
  const int i = (blockIdx.x * 256 + threadIdx.x) * 8;
  if (i + 8 > n) return;
  *(short8*)(out + i) = cvt8_bf16(in + i);
}

// ---------------------------------------------------------------------------
// bf16 MFMA GEMM: C[M x 1024] = A[M x 1024] @ W[1024 x 1024]^T + bias
// 128 x BN tile, BK=32, 256 threads (2x2 waves, each 64 x BN/2).
// XOR source-chunk swizzle on staging -> conflict-light fragment reads.
// OUTK: 0 -> fp32 row-major; 2 -> QKV mode (z<2 bf16 head-major, z==2 bf16 row)
// ---------------------------------------------------------------------------
template <int BN, int OUTK>
__global__ __launch_bounds__(256) void mfma_gemm(
    const __hip_bfloat16* __restrict__ A0, const __hip_bfloat16* __restrict__ A1,
    const __hip_bfloat16* __restrict__ A2, const __hip_bfloat16* __restrict__ W0,
    const __hip_bfloat16* __restrict__ W1, const __hip_bfloat16* __restrict__ W2,
    const float* __restrict__ bias0, const float* __restrict__ bias1,
    const float* __restrict__ bias2, void* C0, void* C1, void* C2, int M) {
  constexpr int K = D_MODEL;
  constexpr int NT = BN / 32;  // B fragment tiles per wave
  __shared__ __align__(16) __hip_bfloat16 As[128 * 32];
  __shared__ __align__(16) __hip_bfloat16 Bs[BN * 32];

  const int z = blockIdx.z;
  const short* A = (const short*)(z == 0 ? A0 : z == 1 ? A1 : A2);
  const short* W = (const short*)(z == 0 ? W0 : z == 1 ? W1 : W2);
  const float* bias = z == 0 ? bias0 : z == 1 ? bias1 : bias2;
  void* C = z == 0 ? C0 : z == 1 ? C1 : C2;

  const int tid = threadIdx.x;
  const int wave = tid >> 6, lane = tid & 63;
  const int col = lane & 15, quad = lane >> 4;
  const int wm = wave >> 1, wn = wave & 1;
  const int m0 = blockIdx.y * 128, n0 = blockIdx.x * BN;

  const int sr = lane >> 2;
  const int ss = lane & 3;
  const int sch = ss ^ ((sr >> 1) & 3);

  floatx4 acc[4][NT];
#pragma unroll
  for (int i = 0; i < 4; i++)
#pragma unroll
    for (int j = 0; j < NT; j++) acc[i][j] = (floatx4){0.f, 0.f, 0.f, 0.f};

  for (int k0 = 0; k0 < K; k0 += 32) {
    if (k0) __syncthreads();
#pragma unroll
    for (int i = 0; i < 2; i++) {
      const int rb = wave * 32 + i * 16;
      const int am = min(m0 + rb + sr, M - 1);
      load_lds16(A + (size_t)am * K + k0 + sch * 8, (char*)As + rb * 64);
    }
#pragma unroll
    for (int i = 0; i < BN / 64; i++) {
      const int rb = (wave * (BN / 64) + i) * 16;
      const int bn = n0 + rb + sr;
      load_lds16(W + (size_t)bn * K + k0 + sch * 8, (char*)Bs + rb * 64);
    }
    __syncthreads();

    short8 af[4], bf[NT];
#pragma unroll
    for (int t = 0; t < 4; t++) {
      const int ra = wm * 64 + t * 16 + col;
      af[t] = *(const short8*)(As + ra * 32 + (quad ^ ((ra >> 1) & 3)) * 8);
    }
#pragma unroll
    for (int t = 0; t < NT; t++) {
      const int rb = wn * (BN / 2) + t * 16 + col;
      bf[t] = *(const short8*)(Bs + rb * 32 + (quad ^ ((rb >> 1) & 3)) * 8);
    }
#pragma unroll
    for (int mt = 0; mt < 4; mt++)
#pragma unroll
      for (int nt = 0; nt < NT; nt++)
        acc[mt][nt] =
            __builtin_amdgcn_mfma_f32_16x16x32_bf16(af[mt], bf[nt], acc[mt][nt], 0, 0, 0);
  }

#pragma unroll
  for (int mt = 0; mt < 4; mt++) {
#pragma unroll
    for (int r = 0; r < 4; r++) {
      const int m = m0 + wm * 64 + mt * 16 + quad * 4 + r;
      if (m >= M) continue;
#pragma unroll
      for (int nt = 0; nt < NT; nt++) {
        const int n = n0 + wn * (BN / 2) + nt * 16 + col;
        const float val = acc[mt][nt][r] + bias[n];
        if (OUTK == 0) {
          ((float*)C)[(size_t)m * D_MODEL + n] = val;
        } else {
          if (z < 2) {  // head-major [h][t][hd] for Q,K
            const int h = n >> 6, hd = n & 63;
            ((__hip_bfloat16*)C)[((size_t)h * T_SEQ + m) * HEAD_DIM + hd] =
                __float2bfloat16(val);
          } else {  // row-major for V (transpose kernel reads this)
            ((__hip_bfloat16*)C)[(size_t)m * D_MODEL + n] = __float2bfloat16(val);
          }
        }
      }
    }
  }
}

// ---------------------------------------------------------------------------
// Transpose V per head: vpr[t][h*64+d] (row-major) -> vt[h][d][t], t-pad zeroed
// ---------------------------------------------------------------------------
__global__ __launch_bounds__(256) void transpose_v(const __hip_bfloat16* __restrict__ vpr,
                                                   __hip_bfloat16* __restrict__ vt) {
  __shared__ __align__(16) __hip_bfloat16 tile[64][72];
  const int t0 = blockIdx.x * 64;
  const int h = blockIdx.y;
  const int tid = threadIdx.x;
  const short* plane = (const short*)vpr;
  short* oplane = (short*)(vt + (size_t)h * HEAD_DIM * VT_STRIDE);

  for (int idx = tid; idx < 64 * 8; idx += 256) {
    const int row = idx >> 3, ch = idx & 7;
    const int t = t0 + row;
    short8 v = {0, 0, 0, 0, 0, 0, 0, 0};
    if (t < T_SEQ) v = *(const short8*)(plane + (size_t)t * D_MODEL + h * 64 + ch * 8);
    *(short8*)&tile[row][ch * 8] = v;
  }
  __syncthreads();
  for (int idx = tid; idx < 64 * 8; idx += 256) {
    const int d = idx >> 3, ch = idx & 7;
    short8 v;
#pragma unroll
    for (int i = 0; i < 8; i++) v[i] = *(const short*)&tile[ch * 8 + i][d];
    *(short8*)(oplane + (size_t)d * VT_STRIDE + t0 + ch * 8) = v;
  }
}

// ---------------------------------------------------------------------------
// Flash attention v3: S^T trick + NO-MAX softmax (logits bounded: std~0.76,
// max ~4.5 -> exp <= ~90, safe in fp32/bf16) -> s-tiles are order-free sums
// -> split-s load balancing with disjoint partial buffers.
// Block b in [0,26) per head: b<8 -> qt=b full range; b>=8 -> qt=8+((b-8)>>1),
// s-range half ((b-8)&1). Partials: half0 -> (O0,l0), half1 -> (O1,l1).
// ---------------------------------------------------------------------------
__global__ __launch_bounds__(512, 4) void flash_attn(
    const __hip_bfloat16* __restrict__ qh, const __hip_bfloat16* __restrict__ kh,
    const __hip_bfloat16* __restrict__ er, const __hip_bfloat16* __restrict__ vt,
    __hip_bfloat16* __restrict__ O0, __hip_bfloat16* __restrict__ O1,
    float* __restrict__ l0g, float* __restrict__ l1g) {
  __shared__ __align__(16) __hip_bfloat16 Ks[2][64 * 128];  // [s][kaug] swizzled
  __shared__ __align__(16) __hip_bfloat16 Vs[2][64 * 64];   // [d][s] swizzled
  __shared__ __align__(16) __hip_bfloat16 Ps[8][1024];      // per-wave frag-major

  const int tid = threadIdx.x;
  const int h = blockIdx.y;
  const int b = blockIdx.x;  // 0..25

  const int qt = (b < 8) ? b : 8 + ((b - 8) >> 1);
  const int tq0 = qt * 128;
  const int jmax = min(tq0 + 127, T_SEQ - 1) >> 6;
  int j0, j1;
  bool alt;
  if (b < 8) {
    j0 = 0; j1 = jmax; alt = false;
  } else {
    const int mid = (jmax + 1) >> 1;
    alt = (b - 8) & 1;
    j0 = alt ? mid : 0;
    j1 = alt ? jmax : mid - 1;
  }

  const int wave = tid >> 6;
  const int lane = tid & 63;
  const int col = lane & 15;
  const int quad = lane >> 4;

  const short* qplane = (const short*)(qh + (size_t)h * T_SEQ * HEAD_DIM);
  const short* kplane = (const short*)(kh + (size_t)h * T_SEQ * HEAD_DIM);
  const short* eplane = (const short*)er;
  const short* vplane = (const short*)(vt + (size_t)h * HEAD_DIM * VT_STRIDE);

  // ---- Q fragments (B-operand): lane holds Qaug[t = tq0+wave*16+col][k]
  const int t_abs = tq0 + wave * 16 + col;
  const int tload = min(t_abs, T_SEQ - 1);
  const bool hiz = (t_abs >= T_SEQ - 1);
  short8 aq[4];
#pragma unroll
  for (int kc = 0; kc < 4; kc++) {
    short8 v = *(const short8*)(qplane + (size_t)tload * 64 + kc * 32 + quad * 8);
    if (kc >= 2 && hiz) v = (short8){0, 0, 0, 0, 0, 0, 0, 0};
    aq[kc] = v;
  }

  floatx4 o[4];
  float l_lane = 0.f;
#pragma unroll
  for (int i = 0; i < 4; i++) o[i] = (floatx4){0.f, 0.f, 0.f, 0.f};

  const int tstrip = tq0 + wave * 16;
  __hip_bfloat16* psw = &Ps[wave][0];

#define STAGE_TILE(JJ, BUF)                                                        \
  {                                                                                \
    const int s0_ = (JJ) * 64;                                                     \
    _Pragma("unroll") for (int ii = 0; ii < 2; ii++) {                             \
      const int i_ = wave * 2 + ii;                                                \
      const int r_ = i_ * 4 + (lane >> 4);                                         \
      const int sl_ = lane & 15;                                                   \
      const int g_ = (sl_ & 8) | ((sl_ ^ (r_ & 7)) & 7);                           \
      const int s_ = min(s0_ + r_, T_SEQ - 1);                                     \
      const short* src_ = (g_ < 8) ? (kplane + (size_t)s_ * 64 + g_ * 8)           \
                                   : (eplane + (size_t)s_ * 64 + (g_ - 8) * 8);    \
      load_lds16(src_, (char*)&Ks[BUF][0] + i_ * 1024);                            \
    }                                                                              \
    {                                                                              \
      const int d_ = wave * 8 + (lane >> 3);                                       \
      const int sl_ = lane & 7;                                                    \
      const int g_ = sl_ ^ (d_ & 7);                                               \
      load_lds16(vplane + (size_t)d_ * VT_STRIDE + s0_ + g_ * 8,                   \
                 (char*)&Vs[BUF][0] + wave * 1024);                                \
    }                                                                              \
  }

  STAGE_TILE(j0, 0)
  int buf = 0;

  for (int j = j0; j <= j1; ++j, buf ^= 1) {
    __syncthreads();
    if (j < j1) STAGE_TILE(j + 1, buf ^ 1)

    const int s0 = j * 64;
    if (s0 > tstrip + 15) continue;  // fully-masked strip

    const __hip_bfloat16* ks = &Ks[buf][0];
    const __hip_bfloat16* vs = &Vs[buf][0];

    // ---- S^T: lane gets S[t=col][s = st*16+quad*4+r]
    floatx4 sacc[4];
#pragma unroll
    for (int st = 0; st < 4; st++) {
      floatx4 c = {0.f, 0.f, 0.f, 0.f};
      const int row = st * 16 + col;
#pragma unroll
      for (int kc = 0; kc < 4; kc++) {
        const int ch = kc * 4 + quad;
        const int slot = (ch & 8) | ((ch ^ (row & 7)) & 7);
        short8 ka = *(const short8*)(ks + row * 128 + slot * 8);
        c = __builtin_amdgcn_mfma_f32_16x16x32_bf16(ka, aq[kc], c, 0, 0, 0);
      }
      sacc[st] = c;
    }

    // ---- causal mask (diagonal-straddling tiles only)
    if (s0 + 63 > tstrip) {
#pragma unroll
      for (int st = 0; st < 4; st++) {
        const int sbase = s0 + st * 16 + quad * 4;
#pragma unroll
        for (int r = 0; r < 4; r++)
          if (sbase + r > t_abs) sacc[st][r] = -INFINITY;
      }
    }

    // ---- no-max softmax numerator: P = exp(S/8); accumulate l per-lane
    float rs = 0.f;
#pragma unroll
    for (int st = 0; st < 4; st++)
#pragma unroll
      for (int r = 0; r < 4; r++) {
        const float p = __expf(sacc[st][r] * 0.125f);
        sacc[st][r] = p;
        rs += p;
      }
    l_lane += rs;

    // ---- P -> per-wave frag-major LDS (wave-private: no barrier)
#pragma unroll
    for (int st = 0; st < 4; st++) {
      __hip_bfloat16 pb[4];
#pragma unroll
      for (int r = 0; r < 4; r++) pb[r] = __float2bfloat16(sacc[st][r]);
      const int kcA = st >> 1;
      const int quadA = (st & 1) * 2 + (quad >> 1);
      const int off = ((kcA * 4 + quadA) * 16 + col) * 8 + (quad & 1) * 4;
      *(short4v*)(psw + off) = *(const short4v*)pb;
    }
    short8 pa[2];
#pragma unroll
    for (int kc = 0; kc < 2; kc++)
      pa[kc] = *(const short8*)(psw + ((kc * 4 + quad) * 16 + col) * 8);

    // ---- PV (no rescale needed)
#pragma unroll
    for (int nt = 0; nt < 4; nt++) {
      const int row = nt * 16 + col;
#pragma unroll
      for (int kc = 0; kc < 2; kc++) {
        const int slot = (kc * 4 + quad) ^ (row & 7);
        short8 vb = *(const short8*)(vs + row * 64 + slot * 8);
        o[nt] = __builtin_amdgcn_mfma_f32_16x16x32_bf16(pa[kc], vb, o[nt], 0, 0, 0);
      }
    }
  }

  // ---- epilogue: store partial l and partial O (bf16, unnormalized)
  l_lane += __shfl_xor(l_lane, 16, 64);
  l_lane += __shfl_xor(l_lane, 32, 64);
  if (lane < 16) {
    const int t = tstrip + lane;
    if (t < T_SEQ) {
      if (!alt)
        l0g[h * T_SEQ + t] = l_lane;
      else
        l1g[h * T1_ROWS + (t - 1024)] = l_lane;
    }
  }
#pragma unroll
  for (int r = 0; r < 4; r++) {
    const int t = tstrip + quad * 4 + r;
    if (t < T_SEQ) {
      if (!alt) {
#pragma unroll
        for (int nt = 0; nt < 4; nt++)
          O0[(size_t)t * D_MODEL + h * 64 + nt * 16 + col] = __float2bfloat16(o[nt][r]);
      } else {
#pragma unroll
        for (int nt = 0; nt < 4; nt++)
          O1[(size_t)(t - 1024) * D_MODEL + h * 64 + nt * 16 + col] =
              __float2bfloat16(o[nt][r]);
      }
    }
  }
}

// ---------------------------------------------------------------------------
// finalize: ctx[t][h*64+d] = (O0 + O1?) / (l0 + l1?)   (8 elems/thread)
// chunk ch covers elems [ch*8, ch*8+8) -> head = ch*8/64 = ch>>3
// ---------------------------------------------------------------------------
__global__ __launch_bounds__(256) void finalize(
    const __hip_bfloat16* __restrict__ O0, const __hip_bfloat16* __restrict__ O1,
    const float* __restrict__ l0g, const float* __restrict__ l1g,
    __hip_bfloat16* __restrict__ ctx) {
  const int idx = blockIdx.x * 256 + threadIdx.x;  // chunk index (8 elems)
  if (idx >= T_SEQ * 128) return;
  const int t = idx >> 7;
  const int ch = idx & 127;
  const int h = ch >> 3;  // FIX (was >>4): 8 chunks per 64-elem head

  float l = l0g[h * T_SEQ + t];
  const __hip_bfloat16* a = O0 + (size_t)t * D_MODEL + ch * 8;
  float acc[8];
#pragma unroll
  for (int i = 0; i < 8; i++) acc[i] = bf2f(a[i]);
  if (t >= 1024) {
    l += l1g[h * T1_ROWS + (t - 1024)];
    const __hip_bfloat16* bsrc = O1 + (size_t)(t - 1024) * D_MODEL + ch * 8;
#pragma unroll
    for (int i = 0; i < 8; i++) acc[i] += bf2f(bsrc[i]);
  }
  const float inv = 1.0f / l;
  __hip_bfloat16 outv[8];
#pragma unroll
  for (int i = 0; i < 8; i++) outv[i] = __float2bfloat16(acc[i] * inv);
  *(short8*)(ctx + (size_t)t * D_MODEL + ch * 8) = *(const short8*)outv;
}

// ---------------------------------------------------------------------------
extern "C" void kernel_launch(void* const* d_in, const int* in_sizes, int n_in,
                              void* d_out, int out_size, void* d_ws, size_t ws_size,
                              hipStream_t stream) {
  const float* q = (const float*)d_in[0];
  const float* k = (const float*)d_in[1];
  const float* v = (const float*)d_in[2];
  const float* Wq_w = (const float*)d_in[4];
  const float* Wq_b = (const float*)d_in[5];
  const float* Wk_w = (const float*)d_in[6];
  const float* Wk_b = (const float*)d_in[7];
  const float* Wv_w = (const float*)d_in[8];
  const float* Wv_b = (const float*)d_in[9];
  const float* Er = (const float*)d_in[10];
  const float* Wo_w = (const float*)d_in[11];
  const float* Wo_b = (const float*)d_in[12];
  float* out = (float*)d_out;

  // ---- workspace carve-up (33.57 MB peak, proven budget)
  char* ws = (char*)d_ws;
  const size_t sz_plane = (size_t)T_SEQ * D_MODEL * 2;  // 4,196,352 B
  const size_t sz_w = (size_t)D_MODEL * D_MODEL * 2;    // 2,097,152 B
  __hip_bfloat16* qbf = (__hip_bfloat16*)ws;                   // dead after QKV GEMM
  __hip_bfloat16* kbf = (__hip_bfloat16*)(ws + sz_plane);      // dead after QKV GEMM
  __hip_bfloat16* vbf = (__hip_bfloat16*)(ws + 2 * sz_plane);  // dead after QKV GEMM
  char* wbase = ws + 3 * sz_plane;
  __hip_bfloat16* wob = (__hip_bfloat16*)(wbase);           // live till out-proj
  __hip_bfloat16* wqb = (__hip_bfloat16*)(wbase + sz_w);    // dead after QKV GEMM
  __hip_bfloat16* wkb = (__hip_bfloat16*)(wbase + 2 * sz_w);
  __hip_bfloat16* wvb = (__hip_bfloat16*)(wbase + 3 * sz_w);
  char* pbase = wbase + 4 * sz_w;
  __hip_bfloat16* qpr = (__hip_bfloat16*)(pbase);                // head-major
  __hip_bfloat16* kpr = (__hip_bfloat16*)(pbase + sz_plane);     // head-major
  __hip_bfloat16* vpr = (__hip_bfloat16*)(pbase + 2 * sz_plane); // row-major

  // overlays on dead front region (12.59 MB), written only after QKV GEMM:
  const size_t sz_vt = (size_t)N_HEAD * HEAD_DIM * VT_STRIDE * 2;  // 4,325,376
  const size_t sz_er = (size_t)T_SEQ * HEAD_DIM * 2;               // 262,272
  const size_t sz_O0 = (size_t)T_SEQ * D_MODEL * 2;                // 4,196,352
  const size_t sz_O1 = (size_t)T1_ROWS * D_MODEL * 2;              // 2,359,296
  const size_t sz_l0 = (size_t)N_HEAD * T_SEQ * 4;                 // 131,136
  __hip_bfloat16* vt = (__hip_bfloat16*)ws;
  __hip_bfloat16* er_bf = (__hip_bfloat16*)(ws + sz_vt);
  __hip_bfloat16* O0 = (__hip_bfloat16*)(ws + sz_vt + sz_er);
  __hip_bfloat16* O1 = (__hip_bfloat16*)(ws + sz_vt + sz_er + sz_O0);
  float* l0g = (float*)(ws + sz_vt + sz_er + sz_O0 + sz_O1);
  float* l1g = (float*)(ws + sz_vt + sz_er + sz_O0 + sz_O1 + sz_l0);
  // ctxb overlays dead wqb/wkb and 2 KB of dead wvb (all dead post-QKV-GEMM)
  __hip_bfloat16* ctxb = (__hip_bfloat16*)(wbase + sz_w);

  const dim3 blk(256);
  const int n_in_elems = T_SEQ * D_MODEL;
  const int n_w_elems = D_MODEL * D_MODEL;
  const int n_er = T_SEQ * HEAD_DIM;

  cast_bf16x<<<dim3((n_in_elems + 2047) / 2048, 3), blk, 0, stream>>>(
      q, k, v, q, qbf, kbf, vbf, qbf, n_in_elems);
  cast_bf16x<<<dim3(n_w_elems / 2048, 4), blk, 0, stream>>>(
      Wq_w, Wk_w, Wv_w, Wo_w, wqb, wkb, wvb, wob, n_w_elems);

  // fused QKV projections: Q,K head-major bf16; V row-major bf16
  mfma_gemm<128, 2><<<dim3(8, 17, 3), blk, 0, stream>>>(
      qbf, kbf, vbf, wqb, wkb, wvb, Wq_b, Wk_b, Wv_b, qpr, kpr, vpr, T_SEQ);

  cast_bf16_one<<<dim3((n_er + 2047) / 2048), blk, 0, stream>>>(Er, er_bf, n_er);
  transpose_v<<<dim3(33, N_HEAD), blk, 0, stream>>>(vpr, vt);

  flash_attn<<<dim3(26, N_HEAD), dim3(512), 0, stream>>>(qpr, kpr, er_bf, vt, O0, O1,
                                                         l0g, l1g);

  finalize<<<dim3((T_SEQ * 128 + 255) / 256), blk, 0, stream>>>(O0, O1, l0g, l1g, ctxb);

  // output projection (fp32 out), 128x64 tiles -> 272 blocks
  mfma_gemm<64, 0><<<dim3(16, 17, 1), blk, 0, stream>>>(
      ctxb, ctxb, ctxb, wob, wob, wob, Wo_b, Wo_b, Wo_b, out, out, out, T_SEQ);
}

// Round 7
// 204.209 us; speedup vs baseline: 24.5404x; 1.0544x over previous
//
#include <hip/hip_runtime.h>
#include <hip/hip_bf16.h>
#include <math.h>

constexpr int T_SEQ = 2049;
constexpr int D_MODEL = 1024;
constexpr int N_HEAD = 16;
constexpr int HEAD_DIM = 64;
constexpr int VT_STRIDE = 2112;  // 2048+64: all V tile reads in-bounds, zero-padded
constexpr int T1_ROWS = 1152;    // rows 1024..2175 for split partial buffers

typedef __attribute__((ext_vector_type(8))) short short8;
typedef __attribute__((ext_vector_type(4))) short short4v;
typedef __attribute__((ext_vector_type(4))) float floatx4;

// async global->LDS, 16B per lane; LDS dest = wave-uniform base + lane*16
__device__ inline void load_lds16(const void* g, void* l) {
  __builtin_amdgcn_global_load_lds(
      (const __attribute__((address_space(1))) unsigned int*)g,
      (__attribute__((address_space(3))) unsigned int*)l, 16, 0, 0);
}

__device__ inline short8 cvt8_bf16(const float* p) {
  float4 a = *(const float4*)p, b = *(const float4*)(p + 4);
  __hip_bfloat16 t[8] = {__float2bfloat16(a.x), __float2bfloat16(a.y),
                         __float2bfloat16(a.z), __float2bfloat16(a.w),
                         __float2bfloat16(b.x), __float2bfloat16(b.y),
                         __float2bfloat16(b.z), __float2bfloat16(b.w)};
  return *(const short8*)t;
}

__device__ inline float bf2f(__hip_bfloat16 x) { return __bfloat162float(x); }

// ---------------------------------------------------------------------------
// Mega-cast: all 7 fp32->bf16 tensors in one launch. grid=(1025,7)
// z: 0..2 -> q,k,v (n=T*D); 3..6 -> Wq,Wk,Wv,Wo (n=D*D)
// ---------------------------------------------------------------------------
__global__ __launch_bounds__(256) void cast_all(
    const float* __restrict__ q, const float* __restrict__ k,
    const float* __restrict__ v, const float* __restrict__ wq,
    const float* __restrict__ wk, const float* __restrict__ wv,
    const float* __restrict__ wo, __hip_bfloat16* __restrict__ qo,
    __hip_bfloat16* __restrict__ ko, __hip_bfloat16* __restrict__ vo,
    __hip_bfloat16* __restrict__ wqo, __hip_bfloat16* __restrict__ wko,
    __hip_bfloat16* __restrict__ wvo, __hip_bfloat16* __restrict__ woo) {
  const int z = blockIdx.y;
  const float* in;
  __hip_bfloat16* out;
  int n;
  switch (z) {
    case 0: in = q; out = qo; n = T_SEQ * D_MODEL; break;
    case 1: in = k; out = ko; n = T_SEQ * D_MODEL; break;
    case 2: in = v; out = vo; n = T_SEQ * D_MODEL; break;
    case 3: in = wq; out = wqo; n = D_MODEL * D_MODEL; break;
    case 4: in = wk; out = wko; n = D_MODEL * D_MODEL; break;
    case 5: in = wv; out = wvo; n = D_MODEL * D_MODEL; break;
    default: in = wo; out = woo; n = D_MODEL * D_MODEL; break;
  }
  const int i = (blockIdx.x * 256 + threadIdx.x) * 8;
  if (i + 8 > n) return;
  *(short8*)(out + i) = cvt8_bf16(in + i);
}

// ---------------------------------------------------------------------------
// bf16 MFMA GEMM: C[M x 1024] = A[M x 1024] @ W[1024 x 1024]^T + bias
// 128 x BN tile, BK=64 (16 K-iters, half the barriers of BK=32), 256 threads.
// Staging: 8 rows x 8 slots per load_lds16; chunk c of row r at slot c^(r&7).
// Row length 128B = exactly 32 banks -> fragment-read conflict profile equals
// the proven BK=32 pattern (8 lanes per 4-bank group, inherent b128 multi-cyc).
// OUTK: 0 -> fp32 row-major; 2 -> QKV mode (z<2 bf16 head-major, z==2 bf16 row)
// ---------------------------------------------------------------------------
template <int BN, int OUTK>
__global__ __launch_bounds__(256) void mfma_gemm(
    const __hip_bfloat16* __restrict__ A0, const __hip_bfloat16* __restrict__ A1,
    const __hip_bfloat16* __restrict__ A2, const __hip_bfloat16* __restrict__ W0,
    const __hip_bfloat16* __restrict__ W1, const __hip_bfloat16* __restrict__ W2,
    const float* __restrict__ bias0, const float* __restrict__ bias1,
    const float* __restrict__ bias2, void* C0, void* C1, void* C2, int M) {
  constexpr int K = D_MODEL;
  constexpr int NT = BN / 32;  // B fragment tiles per wave
  __shared__ __align__(16) __hip_bfloat16 As[128 * 64];
  __shared__ __align__(16) __hip_bfloat16 Bs[BN * 64];

  const int z = blockIdx.z;
  const short* A = (const short*)(z == 0 ? A0 : z == 1 ? A1 : A2);
  const short* W = (const short*)(z == 0 ? W0 : z == 1 ? W1 : W2);
  const float* bias = z == 0 ? bias0 : z == 1 ? bias1 : bias2;
  void* C = z == 0 ? C0 : z == 1 ? C1 : C2;

  const int tid = threadIdx.x;
  const int wave = tid >> 6, lane = tid & 63;
  const int col = lane & 15, quad = lane >> 4;
  const int wm = wave >> 1, wn = wave & 1;
  const int m0 = blockIdx.y * 128, n0 = blockIdx.x * BN;

  // staging lane geometry: 8 rows x 8 slots (16B) per instruction
  const int srow = lane >> 3;        // 0..7
  const int sslot = lane & 7;        // 0..7
  const int sch = sslot ^ srow;      // global chunk fetched into this slot

  floatx4 acc[4][NT];
#pragma unroll
  for (int i = 0; i < 4; i++)
#pragma unroll
    for (int j = 0; j < NT; j++) acc[i][j] = (floatx4){0.f, 0.f, 0.f, 0.f};

  for (int k0 = 0; k0 < K; k0 += 64) {
    if (k0) __syncthreads();
#pragma unroll
    for (int i = 0; i < 4; i++) {
      const int rb = (wave * 4 + i) * 8;  // A tile-row base (row&7 == srow)
      const int am = min(m0 + rb + srow, M - 1);
      load_lds16(A + (size_t)am * K + k0 + sch * 8, (char*)As + rb * 128);
    }
#pragma unroll
    for (int i = 0; i < BN / 32; i++) {
      const int rb = (wave * (BN / 32) + i) * 8;
      const int bn = n0 + rb + srow;
      load_lds16(W + (size_t)bn * K + k0 + sch * 8, (char*)Bs + rb * 128);
    }
    __syncthreads();

#pragma unroll
    for (int kk = 0; kk < 2; kk++) {
      short8 af[4], bf[NT];
#pragma unroll
      for (int t = 0; t < 4; t++) {
        const int ra = wm * 64 + t * 16 + col;
        af[t] = *(const short8*)(As + ra * 64 + ((kk * 4 + quad) ^ (ra & 7)) * 8);
      }
#pragma unroll
      for (int t = 0; t < NT; t++) {
        const int rb = wn * (BN / 2) + t * 16 + col;
        bf[t] = *(const short8*)(Bs + rb * 64 + ((kk * 4 + quad) ^ (rb & 7)) * 8);
      }
#pragma unroll
      for (int mt = 0; mt < 4; mt++)
#pragma unroll
        for (int nt = 0; nt < NT; nt++)
          acc[mt][nt] = __builtin_amdgcn_mfma_f32_16x16x32_bf16(af[mt], bf[nt],
                                                                acc[mt][nt], 0, 0, 0);
    }
  }

#pragma unroll
  for (int mt = 0; mt < 4; mt++) {
#pragma unroll
    for (int r = 0; r < 4; r++) {
      const int m = m0 + wm * 64 + mt * 16 + quad * 4 + r;
      if (m >= M) continue;
#pragma unroll
      for (int nt = 0; nt < NT; nt++) {
        const int n = n0 + wn * (BN / 2) + nt * 16 + col;
        const float val = acc[mt][nt][r] + bias[n];
        if (OUTK == 0) {
          ((float*)C)[(size_t)m * D_MODEL + n] = val;
        } else {
          if (z < 2) {  // head-major [h][t][hd] for Q,K
            const int h = n >> 6, hd = n & 63;
            ((__hip_bfloat16*)C)[((size_t)h * T_SEQ + m) * HEAD_DIM + hd] =
                __float2bfloat16(val);
          } else {  // row-major for V (transpose kernel reads this)
            ((__hip_bfloat16*)C)[(size_t)m * D_MODEL + n] = __float2bfloat16(val);
          }
        }
      }
    }
  }
}

// ---------------------------------------------------------------------------
// Transpose V per head (+ fold in Er fp32->bf16 cast on the extra y-slice).
// grid = (65, 17): y<16,x<33 -> transpose tile; y==16 -> Er cast (65 blocks)
// ---------------------------------------------------------------------------
__global__ __launch_bounds__(256) void transpose_v_er(
    const __hip_bfloat16* __restrict__ vpr, __hip_bfloat16* __restrict__ vt,
    const float* __restrict__ Er, __hip_bfloat16* __restrict__ er_bf) {
  const int tid = threadIdx.x;
  if (blockIdx.y == 16) {
    const int i = (blockIdx.x * 256 + tid) * 8;
    if (i + 8 <= T_SEQ * HEAD_DIM) *(short8*)(er_bf + i) = cvt8_bf16(Er + i);
    return;
  }
  if (blockIdx.x >= 33) return;

  __shared__ __align__(16) __hip_bfloat16 tile[64][72];
  const int t0 = blockIdx.x * 64;
  const int h = blockIdx.y;
  const short* plane = (const short*)vpr;
  short* oplane = (short*)(vt + (size_t)h * HEAD_DIM * VT_STRIDE);

  for (int idx = tid; idx < 64 * 8; idx += 256) {
    const int row = idx >> 3, ch = idx & 7;
    const int t = t0 + row;
    short8 v = {0, 0, 0, 0, 0, 0, 0, 0};
    if (t < T_SEQ) v = *(const short8*)(plane + (size_t)t * D_MODEL + h * 64 + ch * 8);
    *(short8*)&tile[row][ch * 8] = v;
  }
  __syncthreads();
  for (int idx = tid; idx < 64 * 8; idx += 256) {
    const int d = idx >> 3, ch = idx & 7;
    short8 v;
#pragma unroll
    for (int i = 0; i < 8; i++) v[i] = *(const short*)&tile[ch * 8 + i][d];
    *(short8*)(oplane + (size_t)d * VT_STRIDE + t0 + ch * 8) = v;
  }
}

// ---------------------------------------------------------------------------
// Flash attention v3: S^T trick + no-max softmax (logits bounded ~|4.5| ->
// exp <= ~90, fp32-safe) -> order-free s-tiles -> split-s load balancing.
// b<8: qt=b, full s-range, COMPLETE sum -> write normalized ctx directly.
// b>=8: qt=8+((b-8)>>1), s-half (b-8)&1 -> partial (O,l) buffers (t>=1024).
// ---------------------------------------------------------------------------
__global__ __launch_bounds__(512, 4) void flash_attn(
    const __hip_bfloat16* __restrict__ qh, const __hip_bfloat16* __restrict__ kh,
    const __hip_bfloat16* __restrict__ er, const __hip_bfloat16* __restrict__ vt,
    __hip_bfloat16* __restrict__ ctx, __hip_bfloat16* __restrict__ O0,
    __hip_bfloat16* __restrict__ O1, float* __restrict__ l0g,
    float* __restrict__ l1g) {
  __shared__ __align__(16) __hip_bfloat16 Ks[2][64 * 128];  // [s][kaug] swizzled
  __shared__ __align__(16) __hip_bfloat16 Vs[2][64 * 64];   // [d][s] swizzled
  __shared__ __align__(16) __hip_bfloat16 Ps[8][1024];      // per-wave frag-major

  const int tid = threadIdx.x;
  const int h = blockIdx.y;
  const int b = blockIdx.x;  // 0..25

  const int qt = (b < 8) ? b : 8 + ((b - 8) >> 1);
  const int tq0 = qt * 128;
  const int jmax = min(tq0 + 127, T_SEQ - 1) >> 6;
  int j0, j1;
  bool alt;
  if (b < 8) {
    j0 = 0; j1 = jmax; alt = false;
  } else {
    const int mid = (jmax + 1) >> 1;
    alt = (b - 8) & 1;
    j0 = alt ? mid : 0;
    j1 = alt ? jmax : mid - 1;
  }

  const int wave = tid >> 6;
  const int lane = tid & 63;
  const int col = lane & 15;
  const int quad = lane >> 4;

  const short* qplane = (const short*)(qh + (size_t)h * T_SEQ * HEAD_DIM);
  const short* kplane = (const short*)(kh + (size_t)h * T_SEQ * HEAD_DIM);
  const short* eplane = (const short*)er;
  const short* vplane = (const short*)(vt + (size_t)h * HEAD_DIM * VT_STRIDE);

  // ---- Q fragments (B-operand): lane holds Qaug[t = tq0+wave*16+col][k]
  const int t_abs = tq0 + wave * 16 + col;
  const int tload = min(t_abs, T_SEQ - 1);
  const bool hiz = (t_abs >= T_SEQ - 1);
  short8 aq[4];
#pragma unroll
  for (int kc = 0; kc < 4; kc++) {
    short8 v = *(const short8*)(qplane + (size_t)tload * 64 + kc * 32 + quad * 8);
    if (kc >= 2 && hiz) v = (short8){0, 0, 0, 0, 0, 0, 0, 0};
    aq[kc] = v;
  }

  floatx4 o[4];
  float l_lane = 0.f;
#pragma unroll
  for (int i = 0; i < 4; i++) o[i] = (floatx4){0.f, 0.f, 0.f, 0.f};

  const int tstrip = tq0 + wave * 16;
  __hip_bfloat16* psw = &Ps[wave][0];

#define STAGE_TILE(JJ, BUF)                                                        \
  {                                                                                \
    const int s0_ = (JJ) * 64;                                                     \
    _Pragma("unroll") for (int ii = 0; ii < 2; ii++) {                             \
      const int i_ = wave * 2 + ii;                                                \
      const int r_ = i_ * 4 + (lane >> 4);                                         \
      const int sl_ = lane & 15;                                                   \
      const int g_ = (sl_ & 8) | ((sl_ ^ (r_ & 7)) & 7);                           \
      const int s_ = min(s0_ + r_, T_SEQ - 1);                                     \
      const short* src_ = (g_ < 8) ? (kplane + (size_t)s_ * 64 + g_ * 8)           \
                                   : (eplane + (size_t)s_ * 64 + (g_ - 8) * 8);    \
      load_lds16(src_, (char*)&Ks[BUF][0] + i_ * 1024);                            \
    }                                                                              \
    {                                                                              \
      const int d_ = wave * 8 + (lane >> 3);                                       \
      const int sl_ = lane & 7;                                                    \
      const int g_ = sl_ ^ (d_ & 7);                                               \
      load_lds16(vplane + (size_t)d_ * VT_STRIDE + s0_ + g_ * 8,                   \
                 (char*)&Vs[BUF][0] + wave * 1024);                                \
    }                                                                              \
  }

  STAGE_TILE(j0, 0)
  int buf = 0;

  for (int j = j0; j <= j1; ++j, buf ^= 1) {
    __syncthreads();
    if (j < j1) STAGE_TILE(j + 1, buf ^ 1)

    const int s0 = j * 64;
    if (s0 > tstrip + 15) continue;  // fully-masked strip

    const __hip_bfloat16* ks = &Ks[buf][0];
    const __hip_bfloat16* vs = &Vs[buf][0];

    // ---- S^T: lane gets S[t=col][s = st*16+quad*4+r]
    floatx4 sacc[4];
#pragma unroll
    for (int st = 0; st < 4; st++) {
      floatx4 c = {0.f, 0.f, 0.f, 0.f};
      const int row = st * 16 + col;
#pragma unroll
      for (int kc = 0; kc < 4; kc++) {
        const int ch = kc * 4 + quad;
        const int slot = (ch & 8) | ((ch ^ (row & 7)) & 7);
        short8 ka = *(const short8*)(ks + row * 128 + slot * 8);
        c = __builtin_amdgcn_mfma_f32_16x16x32_bf16(ka, aq[kc], c, 0, 0, 0);
      }
      sacc[st] = c;
    }

    // ---- causal mask (diagonal-straddling tiles only)
    if (s0 + 63 > tstrip) {
#pragma unroll
      for (int st = 0; st < 4; st++) {
        const int sbase = s0 + st * 16 + quad * 4;
#pragma unroll
        for (int r = 0; r < 4; r++)
          if (sbase + r > t_abs) sacc[st][r] = -INFINITY;
      }
    }

    // ---- no-max softmax numerator: P = exp(S/8); accumulate l per-lane
    float rs = 0.f;
#pragma unroll
    for (int st = 0; st < 4; st++)
#pragma unroll
      for (int r = 0; r < 4; r++) {
        const float p = __expf(sacc[st][r] * 0.125f);
        sacc[st][r] = p;
        rs += p;
      }
    l_lane += rs;

    // ---- P -> per-wave frag-major LDS (wave-private: no barrier)
#pragma unroll
    for (int st = 0; st < 4; st++) {
      __hip_bfloat16 pb[4];
#pragma unroll
      for (int r = 0; r < 4; r++) pb[r] = __float2bfloat16(sacc[st][r]);
      const int kcA = st >> 1;
      const int quadA = (st & 1) * 2 + (quad >> 1);
      const int off = ((kcA * 4 + quadA) * 16 + col) * 8 + (quad & 1) * 4;
      *(short4v*)(psw + off) = *(const short4v*)pb;
    }
    short8 pa[2];
#pragma unroll
    for (int kc = 0; kc < 2; kc++)
      pa[kc] = *(const short8*)(psw + ((kc * 4 + quad) * 16 + col) * 8);

    // ---- PV (no rescale needed)
#pragma unroll
    for (int nt = 0; nt < 4; nt++) {
      const int row = nt * 16 + col;
#pragma unroll
      for (int kc = 0; kc < 2; kc++) {
        const int slot = (kc * 4 + quad) ^ (row & 7);
        short8 vb = *(const short8*)(vs + row * 64 + slot * 8);
        o[nt] = __builtin_amdgcn_mfma_f32_16x16x32_bf16(pa[kc], vb, o[nt], 0, 0, 0);
      }
    }
  }

  // ---- epilogue
  l_lane += __shfl_xor(l_lane, 16, 64);
  l_lane += __shfl_xor(l_lane, 32, 64);  // full (or half-range) sum for t=tstrip+col

  if (b < 8) {
    // complete sum: write normalized ctx directly (all t < 1024, in-bounds)
    const float linv = 1.0f / l_lane;
    float linv_r[4];
#pragma unroll
    for (int r = 0; r < 4; r++) linv_r[r] = __shfl(linv, quad * 4 + r, 64);
#pragma unroll
    for (int r = 0; r < 4; r++) {
      const int t = tstrip + quad * 4 + r;
#pragma unroll
      for (int nt = 0; nt < 4; nt++)
        ctx[(size_t)t * D_MODEL + h * 64 + nt * 16 + col] =
            __float2bfloat16(o[nt][r] * linv_r[r]);
    }
  } else {
    // partial: store l and unnormalized O into split buffers (rows t-1024)
    if (lane < 16) {
      const int t = tstrip + lane;
      if (t < T_SEQ) {
        if (!alt)
          l0g[h * T1_ROWS + (t - 1024)] = l_lane;
        else
          l1g[h * T1_ROWS + (t - 1024)] = l_lane;
      }
    }
#pragma unroll
    for (int r = 0; r < 4; r++) {
      const int t = tstrip + quad * 4 + r;
      if (t < T_SEQ) {
        __hip_bfloat16* dst = (!alt ? O0 : O1) + (size_t)(t - 1024) * D_MODEL;
#pragma unroll
        for (int nt = 0; nt < 4; nt++)
          dst[h * 64 + nt * 16 + col] = __float2bfloat16(o[nt][r]);
      }
    }
  }
}

// ---------------------------------------------------------------------------
// finalize (t >= 1024 only): ctx[t] = (O0[t-1024]+O1[t-1024]) / (l0+l1)
// ---------------------------------------------------------------------------
__global__ __launch_bounds__(256) void finalize(
    const __hip_bfloat16* __restrict__ O0, const __hip_bfloat16* __restrict__ O1,
    const float* __restrict__ l0g, const float* __restrict__ l1g,
    __hip_bfloat16* __restrict__ ctx) {
  const int idx = blockIdx.x * 256 + threadIdx.x;  // chunk index (8 elems)
  const int tr = idx >> 7;                         // row - 1024
  const int t = 1024 + tr;
  if (t >= T_SEQ) return;
  const int ch = idx & 127;
  const int h = ch >> 3;  // 8 chunks per 64-elem head

  const float l = l0g[h * T1_ROWS + tr] + l1g[h * T1_ROWS + tr];
  const __hip_bfloat16* a = O0 + (size_t)tr * D_MODEL + ch * 8;
  const __hip_bfloat16* bsrc = O1 + (size_t)tr * D_MODEL + ch * 8;
  const float inv = 1.0f / l;
  __hip_bfloat16 outv[8];
#pragma unroll
  for (int i = 0; i < 8; i++)
    outv[i] = __float2bfloat16((bf2f(a[i]) + bf2f(bsrc[i])) * inv);
  *(short8*)(ctx + (size_t)t * D_MODEL + ch * 8) = *(const short8*)outv;
}

// ---------------------------------------------------------------------------
extern "C" void kernel_launch(void* const* d_in, const int* in_sizes, int n_in,
                              void* d_out, int out_size, void* d_ws, size_t ws_size,
                              hipStream_t stream) {
  const float* q = (const float*)d_in[0];
  const float* k = (const float*)d_in[1];
  const float* v = (const float*)d_in[2];
  const float* Wq_w = (const float*)d_in[4];
  const float* Wq_b = (const float*)d_in[5];
  const float* Wk_w = (const float*)d_in[6];
  const float* Wk_b = (const float*)d_in[7];
  const float* Wv_w = (const float*)d_in[8];
  const float* Wv_b = (const float*)d_in[9];
  const float* Er = (const float*)d_in[10];
  const float* Wo_w = (const float*)d_in[11];
  const float* Wo_b = (const float*)d_in[12];
  float* out = (float*)d_out;

  // ---- workspace carve-up (33.57 MB peak, proven budget)
  char* ws = (char*)d_ws;
  const size_t sz_plane = (size_t)T_SEQ * D_MODEL * 2;  // 4,196,352 B
  const size_t sz_w = (size_t)D_MODEL * D_MODEL * 2;    // 2,097,152 B
  __hip_bfloat16* qbf = (__hip_bfloat16*)ws;                   // dead after QKV GEMM
  __hip_bfloat16* kbf = (__hip_bfloat16*)(ws + sz_plane);      // dead after QKV GEMM
  __hip_bfloat16* vbf = (__hip_bfloat16*)(ws + 2 * sz_plane);  // dead after QKV GEMM
  char* wbase = ws + 3 * sz_plane;
  __hip_bfloat16* wob = (__hip_bfloat16*)(wbase);           // live till out-proj
  __hip_bfloat16* wqb = (__hip_bfloat16*)(wbase + sz_w);    // dead after QKV GEMM
  __hip_bfloat16* wkb = (__hip_bfloat16*)(wbase + 2 * sz_w);
  __hip_bfloat16* wvb = (__hip_bfloat16*)(wbase + 3 * sz_w);
  char* pbase = wbase + 4 * sz_w;
  __hip_bfloat16* qpr = (__hip_bfloat16*)(pbase);                // head-major
  __hip_bfloat16* kpr = (__hip_bfloat16*)(pbase + sz_plane);     // head-major
  __hip_bfloat16* vpr = (__hip_bfloat16*)(pbase + 2 * sz_plane); // row-major

  // overlays on dead front region (12.59 MB), written only after QKV GEMM:
  const size_t sz_vt = (size_t)N_HEAD * HEAD_DIM * VT_STRIDE * 2;  // 4,325,376
  const size_t sz_er = (size_t)T_SEQ * HEAD_DIM * 2;               // 262,272
  const size_t sz_Op = (size_t)T1_ROWS * D_MODEL * 2;              // 2,359,296
  const size_t sz_l = (size_t)N_HEAD * T1_ROWS * 4;                // 73,728
  __hip_bfloat16* vt = (__hip_bfloat16*)ws;
  __hip_bfloat16* er_bf = (__hip_bfloat16*)(ws + sz_vt);
  __hip_bfloat16* O0 = (__hip_bfloat16*)(ws + sz_vt + sz_er);
  __hip_bfloat16* O1 = (__hip_bfloat16*)(ws + sz_vt + sz_er + sz_Op);
  float* l0g = (float*)(ws + sz_vt + sz_er + 2 * sz_Op);
  float* l1g = (float*)(ws + sz_vt + sz_er + 2 * sz_Op + sz_l);
  // ctxb overlays dead wqb/wkb (+2KB of dead wvb), all dead post-QKV-GEMM
  __hip_bfloat16* ctxb = (__hip_bfloat16*)(wbase + sz_w);

  const dim3 blk(256);

  // 1) all fp32->bf16 casts in one launch
  cast_all<<<dim3(1025, 7), blk, 0, stream>>>(q, k, v, Wq_w, Wk_w, Wv_w, Wo_w, qbf,
                                              kbf, vbf, wqb, wkb, wvb, wob);

  // 2) fused QKV projections: Q,K head-major bf16; V row-major bf16
  mfma_gemm<128, 2><<<dim3(8, 17, 3), blk, 0, stream>>>(
      qbf, kbf, vbf, wqb, wkb, wvb, Wq_b, Wk_b, Wv_b, qpr, kpr, vpr, T_SEQ);

  // 3) V transpose + Er cast (one launch)
  transpose_v_er<<<dim3(65, 17), blk, 0, stream>>>(vpr, vt, Er, er_bf);

  // 4) flash attention (direct ctx for t<1024; split partials for t>=1024)
  flash_attn<<<dim3(26, N_HEAD), dim3(512), 0, stream>>>(qpr, kpr, er_bf, vt, ctxb,
                                                         O0, O1, l0g, l1g);

  // 5) merge split halves for t>=1024
  finalize<<<dim3((1025 * 128 + 255) / 256), blk, 0, stream>>>(O0, O1, l0g, l1g, ctxb);

  // 6) output projection (fp32 out), 128x64 tiles -> 272 blocks
  mfma_gemm<64, 0><<<dim3(16, 17, 1), blk, 0, stream>>>(
      ctxb, ctxb, ctxb, wob, wob, wob, Wo_b, Wo_b, Wo_b, out, out, out, T_SEQ);
}